// Round 11
// baseline (270.246 us; speedup 1.0000x reference)
//
#include <hip/hip_runtime.h>
#include <math.h>

#define BB 4
#define CIN 128
#define LL 2048
#define HH 8
#define CH 32
#define HID 256

typedef __attribute__((ext_vector_type(8))) __bf16 bf16x8;
typedef __attribute__((ext_vector_type(4))) float f32x4;
typedef __attribute__((ext_vector_type(16))) float f32x16;

static __device__ __forceinline__ unsigned int f2bf(float f) {
    union { __bf16 b; unsigned short s; } u;
    u.b = (__bf16)f;
    return (unsigned int)u.s;
}
static __device__ __forceinline__ float bf2f(unsigned int s) {
    union { float f; unsigned int u; } x;
    x.u = s << 16;
    return x.f;
}

#define MFMA   __builtin_amdgcn_mfma_f32_16x16x32_bf16
#define MFMA32 __builtin_amdgcn_mfma_f32_32x32x16_bf16
#define E2(x)  __builtin_amdgcn_exp2f(x)

// ---------------------------------------------------------------------------
// Kernel 1: QKV 1x1 conv -> bf16 buffers.
// Q: [bh][l][d] bf16, pre-scaled by log2(e)/sqrt(L).  K: [bh][l][d] bf16.
// V: transposed [bh][d][l] bf16.
// ---------------------------------------------------------------------------
__global__ __launch_bounds__(256) void qkv_kernel(
        const float* __restrict__ x, const float* __restrict__ w_qkv,
        const float* __restrict__ b_qkv,
        unsigned short* __restrict__ qb, unsigned short* __restrict__ kb,
        unsigned short* __restrict__ vtb) {
    __shared__ float wl[32 * 128];
    __shared__ float tr[32 * 65];
    const int t = threadIdx.x;
    const int lt = blockIdx.x;           // 0..31
    const int g  = blockIdx.y;           // 0..23 : sel*8 + h
    const int b  = blockIdx.z;
    const int sel = g >> 3, h = g & 7;
    const int obase = sel * 256 + h * 32;
    const int l0 = lt * 64;

    const float4* wsrc = (const float4*)(w_qkv + (size_t)obase * CIN);
    float4* wdst = (float4*)wl;
    #pragma unroll
    for (int r = 0; r < 4; ++r) wdst[r * 256 + t] = wsrc[r * 256 + t];
    __syncthreads();

    const int ll = t & 63, og = t >> 6;
    float acc[8] = {0.f,0.f,0.f,0.f,0.f,0.f,0.f,0.f};
    const float* xp = x + (size_t)b * CIN * LL + l0 + ll;
    for (int i = 0; i < CIN; i += 4) {
        float x0 = xp[(size_t)(i+0) * LL];
        float x1 = xp[(size_t)(i+1) * LL];
        float x2 = xp[(size_t)(i+2) * LL];
        float x3 = xp[(size_t)(i+3) * LL];
        #pragma unroll
        for (int j = 0; j < 8; ++j) {
            float4 w4 = *(const float4*)(wl + (og * 8 + j) * 128 + i);
            acc[j] += w4.x * x0 + w4.y * x1 + w4.z * x2 + w4.w * x3;
        }
    }
    // log2(e)/sqrt(2048)
    const float scale = (sel == 0) ? 0.03187935835f : 1.0f;
    #pragma unroll
    for (int j = 0; j < 8; ++j) {
        int oc = og * 8 + j;
        tr[oc * 65 + ll] = (acc[j] + b_qkv[obase + oc]) * scale;   // [c][l]
    }
    __syncthreads();
    if (sel == 2) {
        unsigned short* dst = vtb + ((size_t)(b * HH + h) * CH) * LL + l0;
        #pragma unroll
        for (int r = 0; r < 8; ++r) {
            int flat = r * 256 + t;           // c*64 + l
            int c = flat >> 6, l = flat & 63;
            dst[(size_t)c * LL + l] = (unsigned short)f2bf(tr[c * 65 + l]);
        }
    } else {
        unsigned short* dst = (sel == 0 ? qb : kb)
                              + ((size_t)(b * HH + h) * LL + l0) * CH;
        #pragma unroll
        for (int r = 0; r < 8; ++r) {
            int flat = r * 256 + t;           // lr*32 + c
            int c = flat & 31, lr = flat >> 5;
            dst[flat] = (unsigned short)f2bf(tr[c * 65 + lr]);
        }
    }
}

// ---------------------------------------------------------------------------
// Kernel 2: softmax denominators.  Block = (bh, 128-q tile); each of the 8
// waves covers ALL 128 q and a DISJOINT 256-a slice (K stream read once per
// block, not 4x redundantly).  8-way LDS Z-combine, then scale V^T in place.
// ---------------------------------------------------------------------------
__global__ __launch_bounds__(512, 4) void denom_mfma(
        const unsigned short* __restrict__ qb,
        const unsigned short* __restrict__ kb,
        unsigned short* __restrict__ vtb) {
    __shared__ float zz[8][128];
    const int t = threadIdx.x, wave = t >> 6, lane = t & 63;
    const int id = blockIdx.x;                 // 0..511
    const int bh = (id & 7) * 4 + (id >> 7);   // xcd-swizzled
    const int qt = (id >> 3) & 15;             // 128-q tile
    const int r = lane & 15, g = lane >> 4;

    // A-frags: 8 q-groups of 16 rows each
    bf16x8 af[8];
    #pragma unroll
    for (int f = 0; f < 8; ++f)
        af[f] = *(const bf16x8*)(qb + ((size_t)bh * LL + qt * 128 + f * 16 + r) * CH + 8 * g);

    const unsigned short* kp = kb + ((size_t)bh * LL + wave * 256 + r) * CH + 8 * g;

    float z[8][4];
    #pragma unroll
    for (int f = 0; f < 8; ++f) { z[f][0]=0.f; z[f][1]=0.f; z[f][2]=0.f; z[f][3]=0.f; }

    const f32x4 zero = {0.f, 0.f, 0.f, 0.f};
    bf16x8 kn0 = *(const bf16x8*)(kp);
    bf16x8 kn1 = *(const bf16x8*)(kp + 16 * CH);
    bf16x8 kn2 = *(const bf16x8*)(kp + 32 * CH);
    bf16x8 kn3 = *(const bf16x8*)(kp + 48 * CH);
    #pragma unroll
    for (int it = 0; it < 4; ++it) {
        bf16x8 c0 = kn0, c1 = kn1, c2 = kn2, c3 = kn3;
        if (it < 3) {
            const unsigned short* np = kp + (size_t)(it + 1) * 64 * CH;
            kn0 = *(const bf16x8*)(np);
            kn1 = *(const bf16x8*)(np + 16 * CH);
            kn2 = *(const bf16x8*)(np + 32 * CH);
            kn3 = *(const bf16x8*)(np + 48 * CH);
        }
        #pragma unroll
        for (int s = 0; s < 4; ++s) {
            bf16x8 cc = (s == 0) ? c0 : (s == 1) ? c1 : (s == 2) ? c2 : c3;
            #pragma unroll
            for (int f = 0; f < 8; ++f) {
                f32x4 d = MFMA(af[f], cc, zero, 0, 0, 0);
                z[f][0] += E2(d[0]); z[f][1] += E2(d[1]);
                z[f][2] += E2(d[2]); z[f][3] += E2(d[3]);
            }
        }
    }
    // reduce over a within wave (lanes differing in r)
    #pragma unroll
    for (int m = 1; m < 16; m <<= 1) {
        #pragma unroll
        for (int f = 0; f < 8; ++f) {
            z[f][0] += __shfl_xor(z[f][0], m);
            z[f][1] += __shfl_xor(z[f][1], m);
            z[f][2] += __shfl_xor(z[f][2], m);
            z[f][3] += __shfl_xor(z[f][3], m);
        }
    }
    if (r == 0) {
        #pragma unroll
        for (int f = 0; f < 8; ++f)
            *(float4*)&zz[wave][f * 16 + 4 * g] =
                make_float4(z[f][0], z[f][1], z[f][2], z[f][3]);
    }
    __syncthreads();
    if (t < 128) {
        float s = zz[0][t] + zz[1][t] + zz[2][t] + zz[3][t]
                + zz[4][t] + zz[5][t] + zz[6][t] + zz[7][t];
        zz[0][t] = 1.0f / s;
    }
    __syncthreads();

    // scale vtb[bh][d][qt*128 .. +127]: 512 thr x 8 elems = 32 d x 128 q
    const int d = t >> 4, qo = (t & 15) * 8;
    unsigned short* vrow = vtb + ((size_t)bh * CH + d) * LL + qt * 128 + qo;
    uint4 v = *(const uint4*)vrow;
    const float* zp = &zz[0][qo];
    unsigned int w0, w1, w2, w3;
    w0 = f2bf(bf2f(v.x & 0xFFFFu) * zp[0]) | (f2bf(bf2f(v.x >> 16) * zp[1]) << 16);
    w1 = f2bf(bf2f(v.y & 0xFFFFu) * zp[2]) | (f2bf(bf2f(v.y >> 16) * zp[3]) << 16);
    w2 = f2bf(bf2f(v.z & 0xFFFFu) * zp[4]) | (f2bf(bf2f(v.z >> 16) * zp[5]) << 16);
    w3 = f2bf(bf2f(v.w & 0xFFFFu) * zp[6]) | (f2bf(bf2f(v.w >> 16) * zp[7]) << 16);
    *(uint4*)vrow = make_uint4(w0, w1, w2, w3);
}

// ---------------------------------------------------------------------------
// Kernel 3: attn^T via 32x32x16 MFMA + in-register softmax transpose.
// 8-wave blocks (256 a-cols): Q-tile and V-tile staged ONCE per block into
// padded LDS (stride 40 ushort) and shared by all 8 waves -> 8x less
// global traffic (the R10-measured limiter).  Double-buffered, reg-staged.
// ---------------------------------------------------------------------------
__global__ __launch_bounds__(512, 4) void attn_mfma(
        const unsigned short* __restrict__ qb,
        const unsigned short* __restrict__ kb,
        const unsigned short* __restrict__ vtb,
        float* __restrict__ attnT) {
    __shared__ unsigned short qlds[2][32][40];
    __shared__ unsigned short vlds[2][32][40];
    const int t = threadIdx.x, wave = t >> 6, lane = t & 63;
    const int ln = lane & 31, hi = lane >> 5;
    const int id = blockIdx.x;                    // 0..511
    const int bhqh = (id & 7) * 8 + (id >> 6);    // xcd-swizzled (bh,qh)
    const int at = (id >> 3) & 7;
    const int bh = bhqh >> 1, qh = bhqh & 1;
    const int b = bh >> 3, h = bh & 7;
    const int a0 = at * 256 + wave * 32;
    const int q00 = qh * 1024;

    // K B-frag (loop-invariant): col a=a0+ln, k dims 8hi.. / 16+8hi..
    const unsigned short* kp = kb + ((size_t)bh * LL + a0 + ln) * CH + 8 * hi;
    const bf16x8 kf0 = *(const bf16x8*)kp;
    const bf16x8 kf1 = *(const bf16x8*)(kp + 16);

    // staging: waves 0-1 -> Q tile (2KB), waves 2-3 -> V tile (2KB), 16B/lane
    const int si = t & 127;
    const unsigned short* qsrc = qb + ((size_t)bh * LL + q00) * CH + si * 8;
    const unsigned short* vsrc = vtb + ((size_t)bh * CH + (si >> 2)) * LL
                                 + q00 + (si & 3) * 8;
    const int sdst = (si >> 2) * 40 + (si & 3) * 8;     // ushort offset
    unsigned short* const ql0 = &qlds[0][0][0];
    unsigned short* const ql1 = &qlds[1][0][0];
    unsigned short* const vl0 = &vlds[0][0][0];
    unsigned short* const vl1 = &vlds[1][0][0];

    f32x16 acc = {0.f,0.f,0.f,0.f,0.f,0.f,0.f,0.f,0.f,0.f,0.f,0.f,0.f,0.f,0.f,0.f};
    const f32x16 zero16 = {0.f,0.f,0.f,0.f,0.f,0.f,0.f,0.f,0.f,0.f,0.f,0.f,0.f,0.f,0.f,0.f};

#define CVTPK(dst, lo_, hi_) \
    asm("v_cvt_pk_bf16_f32 %0, %1, %2" : "=v"(dst) : "v"(lo_), "v"(hi_))
#define SWAPH(a_, b_) \
    asm("v_permlane32_swap_b32 %0, %1" : "+v"(a_), "+v"(b_))

    // prologue: stage tile 0 into buf 0
    {
        uint4 sreg;
        if (wave < 2)      sreg = *(const uint4*)(qsrc);
        else if (wave < 4) sreg = *(const uint4*)(vsrc);
        if (wave < 2)      *(uint4*)(ql0 + sdst) = sreg;
        else if (wave < 4) *(uint4*)(vl0 + sdst) = sreg;
    }
    __syncthreads();

    const int rdq = ln * 40 + 8 * hi;   // qa0/vb0 ushort offset; +16 for *1
    #pragma unroll 2
    for (int n = 0; n < 32; ++n) {
        const int cur = n & 1;
        // issue next-tile loads early (latency hides under compute)
        uint4 nreg;
        if (n < 31) {
            if (wave < 2)      nreg = *(const uint4*)(qsrc + (n + 1) * 1024);
            else if (wave < 4) nreg = *(const uint4*)(vsrc + (n + 1) * 32);
        }
        // fragments from LDS (shared by all 8 waves)
        const unsigned short* qc = cur ? ql1 : ql0;
        const unsigned short* vc = cur ? vl1 : vl0;
        bf16x8 qa0 = *(const bf16x8*)(qc + rdq);
        bf16x8 qa1 = *(const bf16x8*)(qc + rdq + 16);
        bf16x8 vb0 = *(const bf16x8*)(vc + rdq);
        bf16x8 vb1 = *(const bf16x8*)(vc + rdq + 16);
        // S = Q.K^T (rows q in regs, col a = ln)
        f32x16 s = MFMA32(qa0, kf0, zero16, 0, 0, 0);
        s = MFMA32(qa1, kf1, s, 0, 0, 0);
        // P = exp2(S) -> bf16 pack -> lane-half swap = in-register transpose
        unsigned int w0, w1, w2, w3, w4, w5, w6, w7;
        {
            float p0  = E2(s[0]),  p1  = E2(s[1]),  p2  = E2(s[2]),  p3  = E2(s[3]);
            float p4  = E2(s[4]),  p5  = E2(s[5]),  p6  = E2(s[6]),  p7  = E2(s[7]);
            float p8  = E2(s[8]),  p9  = E2(s[9]),  p10 = E2(s[10]), p11 = E2(s[11]);
            float p12 = E2(s[12]), p13 = E2(s[13]), p14 = E2(s[14]), p15 = E2(s[15]);
            CVTPK(w0, p0,  p1);  CVTPK(w1, p2,  p3);
            CVTPK(w2, p4,  p5);  CVTPK(w3, p6,  p7);
            CVTPK(w4, p8,  p9);  CVTPK(w5, p10, p11);
            CVTPK(w6, p12, p13); CVTPK(w7, p14, p15);
            SWAPH(w0, w2); SWAPH(w1, w3); SWAPH(w4, w6); SWAPH(w5, w7);
        }
        union { uint4 u; bf16x8 v; } pa0, pa1;
        pa0.u = make_uint4(w0, w1, w2, w3);
        pa1.u = make_uint4(w4, w5, w6, w7);
        __builtin_amdgcn_s_setprio(1);
        acc = MFMA32(pa0.v, vb0, acc, 0, 0, 0);
        acc = MFMA32(pa1.v, vb1, acc, 0, 0, 0);
        __builtin_amdgcn_s_setprio(0);
        __syncthreads();
        if (n < 31) {
            unsigned short* qd = cur ? ql0 : ql1;
            unsigned short* vd = cur ? vl0 : vl1;
            if (wave < 2)      *(uint4*)(qd + sdst) = nreg;
            else if (wave < 4) *(uint4*)(vd + sdst) = nreg;
        }
        __syncthreads();
    }

#undef SWAPH
#undef CVTPK

    // D[a][d]: col d = ln, row a = (reg&3) + 8*(reg>>2) + 4*hi
    float* ob = attnT + ((size_t)qh * BB * HID + (size_t)b * HID + h * CH + ln) * LL
                + a0 + 4 * hi;
    *(f32x4*)(ob +  0) = __builtin_shufflevector(acc, acc,  0,  1,  2,  3);
    *(f32x4*)(ob +  8) = __builtin_shufflevector(acc, acc,  4,  5,  6,  7);
    *(f32x4*)(ob + 16) = __builtin_shufflevector(acc, acc,  8,  9, 10, 11);
    *(f32x4*)(ob + 24) = __builtin_shufflevector(acc, acc, 12, 13, 14, 15);
}

// ---------------------------------------------------------------------------
// Kernel 4: out[b,o,l] = BN( w_out @ (sum of 2 f32 partials) + b_out + x )
// ---------------------------------------------------------------------------
__global__ __launch_bounds__(256) void out_kernel(
        const float* __restrict__ attnT, const float* __restrict__ x,
        const float* __restrict__ w_out, const float* __restrict__ b_out,
        const float* __restrict__ bnw, const float* __restrict__ bnb,
        const float* __restrict__ bnm, const float* __restrict__ bnv,
        float* __restrict__ out) {
    __shared__ float wl[8 * 256];
    const int t = threadIdx.x;
    const int l0 = blockIdx.x * 256;
    const int o0 = blockIdx.y * 8;
    const int b  = blockIdx.z;

    const float4* ws = (const float4*)(w_out + (size_t)o0 * HID);
    float4* wd = (float4*)wl;
    #pragma unroll
    for (int r = 0; r < 2; ++r) wd[r * 256 + t] = ws[r * 256 + t];
    __syncthreads();

    float acc[8];
    #pragma unroll
    for (int j = 0; j < 8; ++j) acc[j] = 0.f;

    const size_t PART = (size_t)BB * HID * LL;   // floats per partial
    const float* ap = attnT + (size_t)b * HID * LL + l0 + t;
    for (int i = 0; i < HID; i += 4) {
        const float* p0 = ap + (size_t)(i+0) * LL;
        const float* p1 = ap + (size_t)(i+1) * LL;
        const float* p2 = ap + (size_t)(i+2) * LL;
        const float* p3 = ap + (size_t)(i+3) * LL;
        float a0 = p0[0] + p0[PART];
        float a1 = p1[0] + p1[PART];
        float a2 = p2[0] + p2[PART];
        float a3 = p3[0] + p3[PART];
        #pragma unroll
        for (int j = 0; j < 8; ++j) {
            float4 w4 = *(const float4*)(wl + j * 256 + i);
            acc[j] += w4.x * a0 + w4.y * a1 + w4.z * a2 + w4.w * a3;
        }
    }
    #pragma unroll
    for (int j = 0; j < 8; ++j) {
        const int o = o0 + j;
        const float inv = bnw[o] / sqrtf(bnv[o] + 1e-5f);
        const float sh  = bnb[o] - bnm[o] * inv;
        const size_t idx = ((size_t)b * CIN + o) * LL + l0 + t;
        float val = acc[j] + b_out[o] + x[idx];
        out[idx] = val * inv + sh;
    }
}

// ---------------------------------------------------------------------------
extern "C" void kernel_launch(void* const* d_in, const int* in_sizes, int n_in,
                              void* d_out, int out_size, void* d_ws, size_t ws_size,
                              hipStream_t stream) {
    const float* x      = (const float*)d_in[0];
    const float* w_qkv  = (const float*)d_in[1];
    const float* b_qkv  = (const float*)d_in[2];
    const float* w_out  = (const float*)d_in[3];
    const float* b_out  = (const float*)d_in[4];
    const float* bnw    = (const float*)d_in[5];
    const float* bnb    = (const float*)d_in[6];
    const float* bnm    = (const float*)d_in[7];
    const float* bnv    = (const float*)d_in[8];
    float* out = (float*)d_out;

    const size_t NBH = (size_t)BB * HH;          // 32
    const size_t QKV_ELEMS = NBH * LL * CH;      // 2,097,152 bf16 elems each
    unsigned short* qb    = (unsigned short*)d_ws;
    unsigned short* kb    = qb + QKV_ELEMS;
    unsigned short* vtb   = kb + QKV_ELEMS;
    float* attnT = (float*)(vtb + QKV_ELEMS);    // 2 x 8 MB f32 partials

    qkv_kernel<<<dim3(32, 24, BB), 256, 0, stream>>>(x, w_qkv, b_qkv, qb, kb, vtb);
    denom_mfma<<<dim3(512), 512, 0, stream>>>(qb, kb, vtb);
    attn_mfma<<<dim3(512), 512, 0, stream>>>(qb, kb, vtb, attnT);
    out_kernel<<<dim3(8, 16, BB), 256, 0, stream>>>(attnT, x, w_out, b_out,
                                                    bnw, bnb, bnm, bnv, out);
}

// Round 12
// 127.818 us; speedup vs baseline: 2.1143x; 2.1143x over previous
//
#include <hip/hip_runtime.h>
#include <math.h>

#define BB 4
#define CIN 128
#define LL 2048
#define HH 8
#define CH 32
#define HID 256

typedef __attribute__((ext_vector_type(8))) __bf16 bf16x8;
typedef __attribute__((ext_vector_type(4))) float f32x4;
typedef __attribute__((ext_vector_type(16))) float f32x16;

static __device__ __forceinline__ unsigned int f2bf(float f) {
    union { __bf16 b; unsigned short s; } u;
    u.b = (__bf16)f;
    return (unsigned int)u.s;
}
static __device__ __forceinline__ float bf2f(unsigned int s) {
    union { float f; unsigned int u; } x;
    x.u = s << 16;
    return x.f;
}

#define MFMA   __builtin_amdgcn_mfma_f32_16x16x32_bf16
#define MFMA32 __builtin_amdgcn_mfma_f32_32x32x16_bf16
#define E2(x)  __builtin_amdgcn_exp2f(x)

// ---------------------------------------------------------------------------
// Kernel 1: QKV 1x1 conv -> bf16 buffers.
// Q: [bh][l][d] bf16, pre-scaled by log2(e)/sqrt(L).  K: [bh][l][d] bf16.
// V: transposed [bh][d][l] bf16.
// ---------------------------------------------------------------------------
__global__ __launch_bounds__(256) void qkv_kernel(
        const float* __restrict__ x, const float* __restrict__ w_qkv,
        const float* __restrict__ b_qkv,
        unsigned short* __restrict__ qb, unsigned short* __restrict__ kb,
        unsigned short* __restrict__ vtb) {
    __shared__ float wl[32 * 128];
    __shared__ float tr[32 * 65];
    const int t = threadIdx.x;
    const int lt = blockIdx.x;           // 0..31
    const int g  = blockIdx.y;           // 0..23 : sel*8 + h
    const int b  = blockIdx.z;
    const int sel = g >> 3, h = g & 7;
    const int obase = sel * 256 + h * 32;
    const int l0 = lt * 64;

    const float4* wsrc = (const float4*)(w_qkv + (size_t)obase * CIN);
    float4* wdst = (float4*)wl;
    #pragma unroll
    for (int r = 0; r < 4; ++r) wdst[r * 256 + t] = wsrc[r * 256 + t];
    __syncthreads();

    const int ll = t & 63, og = t >> 6;
    float acc[8] = {0.f,0.f,0.f,0.f,0.f,0.f,0.f,0.f};
    const float* xp = x + (size_t)b * CIN * LL + l0 + ll;
    for (int i = 0; i < CIN; i += 4) {
        float x0 = xp[(size_t)(i+0) * LL];
        float x1 = xp[(size_t)(i+1) * LL];
        float x2 = xp[(size_t)(i+2) * LL];
        float x3 = xp[(size_t)(i+3) * LL];
        #pragma unroll
        for (int j = 0; j < 8; ++j) {
            float4 w4 = *(const float4*)(wl + (og * 8 + j) * 128 + i);
            acc[j] += w4.x * x0 + w4.y * x1 + w4.z * x2 + w4.w * x3;
        }
    }
    // log2(e)/sqrt(2048)
    const float scale = (sel == 0) ? 0.03187935835f : 1.0f;
    #pragma unroll
    for (int j = 0; j < 8; ++j) {
        int oc = og * 8 + j;
        tr[oc * 65 + ll] = (acc[j] + b_qkv[obase + oc]) * scale;   // [c][l]
    }
    __syncthreads();
    if (sel == 2) {
        unsigned short* dst = vtb + ((size_t)(b * HH + h) * CH) * LL + l0;
        #pragma unroll
        for (int r = 0; r < 8; ++r) {
            int flat = r * 256 + t;           // c*64 + l
            int c = flat >> 6, l = flat & 63;
            dst[(size_t)c * LL + l] = (unsigned short)f2bf(tr[c * 65 + l]);
        }
    } else {
        unsigned short* dst = (sel == 0 ? qb : kb)
                              + ((size_t)(b * HH + h) * LL + l0) * CH;
        #pragma unroll
        for (int r = 0; r < 8; ++r) {
            int flat = r * 256 + t;           // lr*32 + c
            int c = flat & 31, lr = flat >> 5;
            dst[flat] = (unsigned short)f2bf(tr[c * 65 + lr]);
        }
    }
}

// ---------------------------------------------------------------------------
// Kernel 2 (reverted to R10-proven version): softmax denominators via MFMA
// (K-frag prefetch pipelined), then scale V^T in place.  512 threads:
// waves 0-3 sum a in [0,1024), waves 4-7 in [1024,2048).
// ---------------------------------------------------------------------------
__global__ __launch_bounds__(512) void denom_mfma(
        const unsigned short* __restrict__ qb,
        const unsigned short* __restrict__ kb,
        unsigned short* __restrict__ vtb) {
    __shared__ float zz[2][64];
    const int t = threadIdx.x, wave = t >> 6, lane = t & 63;
    const int id = blockIdx.x;
    const int bh = (id & 7) * 4 + ((id >> 3) >> 5);
    const int qt = (id >> 3) & 31;
    const int ah = wave >> 2, wsub = wave & 3;
    const int q0 = qt * 64 + wsub * 16;
    const int r = lane & 15, g = lane >> 4;

    bf16x8 afrag = *(const bf16x8*)(qb + ((size_t)bh * LL + q0 + r) * CH + 8 * g);
    const unsigned short* kp = kb + ((size_t)bh * LL + ah * 1024 + r) * CH + 8 * g;

    float z0 = 0.f, z1 = 0.f, z2 = 0.f, z3 = 0.f;
    const f32x4 zero = {0.f, 0.f, 0.f, 0.f};
    bf16x8 n0 = *(const bf16x8*)(kp);
    bf16x8 n1 = *(const bf16x8*)(kp + 16 * CH);
    bf16x8 n2 = *(const bf16x8*)(kp + 32 * CH);
    bf16x8 n3 = *(const bf16x8*)(kp + 48 * CH);
    for (int it = 0; it < 16; ++it) {
        bf16x8 c0 = n0, c1 = n1, c2 = n2, c3 = n3;
        if (it < 15) {
            const unsigned short* np = kp + (size_t)(it + 1) * 64 * CH;
            n0 = *(const bf16x8*)(np);
            n1 = *(const bf16x8*)(np + 16 * CH);
            n2 = *(const bf16x8*)(np + 32 * CH);
            n3 = *(const bf16x8*)(np + 48 * CH);
        }
        f32x4 d0 = MFMA(afrag, c0, zero, 0, 0, 0);
        f32x4 d1 = MFMA(afrag, c1, zero, 0, 0, 0);
        f32x4 d2 = MFMA(afrag, c2, zero, 0, 0, 0);
        f32x4 d3 = MFMA(afrag, c3, zero, 0, 0, 0);
        z0 += E2(d0[0]) + E2(d1[0]) + E2(d2[0]) + E2(d3[0]);
        z1 += E2(d0[1]) + E2(d1[1]) + E2(d2[1]) + E2(d3[1]);
        z2 += E2(d0[2]) + E2(d1[2]) + E2(d2[2]) + E2(d3[2]);
        z3 += E2(d0[3]) + E2(d1[3]) + E2(d2[3]) + E2(d3[3]);
    }
    #pragma unroll
    for (int m = 1; m < 16; m <<= 1) {
        z0 += __shfl_xor(z0, m); z1 += __shfl_xor(z1, m);
        z2 += __shfl_xor(z2, m); z3 += __shfl_xor(z3, m);
    }
    if (r == 0) {
        *(float4*)&zz[ah][wsub * 16 + 4 * g] = make_float4(z0, z1, z2, z3);
    }
    __syncthreads();

    const int d = t >> 4, qo = (t & 15) * 4;
    const float i0 = 1.f / (zz[0][qo + 0] + zz[1][qo + 0]);
    const float i1 = 1.f / (zz[0][qo + 1] + zz[1][qo + 1]);
    const float i2 = 1.f / (zz[0][qo + 2] + zz[1][qo + 2]);
    const float i3 = 1.f / (zz[0][qo + 3] + zz[1][qo + 3]);
    unsigned short* vrow = vtb + ((size_t)bh * CH + d) * LL + qt * 64 + qo;
    uint2 v = *(const uint2*)vrow;
    unsigned int w0, w1;
    w0 = f2bf(bf2f(v.x & 0xFFFFu) * i0) | (f2bf(bf2f(v.x >> 16) * i1) << 16);
    w1 = f2bf(bf2f(v.y & 0xFFFFu) * i2) | (f2bf(bf2f(v.y >> 16) * i3) << 16);
    *(uint2*)vrow = make_uint2(w0, w1);
}

// ---------------------------------------------------------------------------
// Kernel 3 (unchanged from R11 -- isolating its effect this round):
// attn^T via 32x32x16 MFMA + in-register softmax transpose.
// 8-wave blocks (256 a-cols): Q-tile and V-tile staged ONCE per block into
// padded LDS (contiguous 64B-per-line-touch staging loads) and shared by all
// 8 waves -> 8x fewer L1 line-touches (the R10-measured limiter).
// ---------------------------------------------------------------------------
__global__ __launch_bounds__(512, 4) void attn_mfma(
        const unsigned short* __restrict__ qb,
        const unsigned short* __restrict__ kb,
        const unsigned short* __restrict__ vtb,
        float* __restrict__ attnT) {
    __shared__ unsigned short qlds[2][32][40];
    __shared__ unsigned short vlds[2][32][40];
    const int t = threadIdx.x, wave = t >> 6, lane = t & 63;
    const int ln = lane & 31, hi = lane >> 5;
    const int id = blockIdx.x;                    // 0..511
    const int bhqh = (id & 7) * 8 + (id >> 6);    // xcd-swizzled (bh,qh)
    const int at = (id >> 3) & 7;
    const int bh = bhqh >> 1, qh = bhqh & 1;
    const int b = bh >> 3, h = bh & 7;
    const int a0 = at * 256 + wave * 32;
    const int q00 = qh * 1024;

    // K B-frag (loop-invariant): col a=a0+ln, k dims 8hi.. / 16+8hi..
    const unsigned short* kp = kb + ((size_t)bh * LL + a0 + ln) * CH + 8 * hi;
    const bf16x8 kf0 = *(const bf16x8*)kp;
    const bf16x8 kf1 = *(const bf16x8*)(kp + 16);

    // staging: waves 0-1 -> Q tile (2KB), waves 2-3 -> V tile (2KB), 16B/lane
    const int si = t & 127;
    const unsigned short* qsrc = qb + ((size_t)bh * LL + q00) * CH + si * 8;
    const unsigned short* vsrc = vtb + ((size_t)bh * CH + (si >> 2)) * LL
                                 + q00 + (si & 3) * 8;
    const int sdst = (si >> 2) * 40 + (si & 3) * 8;     // ushort offset
    unsigned short* const ql0 = &qlds[0][0][0];
    unsigned short* const ql1 = &qlds[1][0][0];
    unsigned short* const vl0 = &vlds[0][0][0];
    unsigned short* const vl1 = &vlds[1][0][0];

    f32x16 acc = {0.f,0.f,0.f,0.f,0.f,0.f,0.f,0.f,0.f,0.f,0.f,0.f,0.f,0.f,0.f,0.f};
    const f32x16 zero16 = {0.f,0.f,0.f,0.f,0.f,0.f,0.f,0.f,0.f,0.f,0.f,0.f,0.f,0.f,0.f,0.f};

#define CVTPK(dst, lo_, hi_) \
    asm("v_cvt_pk_bf16_f32 %0, %1, %2" : "=v"(dst) : "v"(lo_), "v"(hi_))
#define SWAPH(a_, b_) \
    asm("v_permlane32_swap_b32 %0, %1" : "+v"(a_), "+v"(b_))

    // prologue: stage tile 0 into buf 0
    {
        uint4 sreg;
        if (wave < 2)      sreg = *(const uint4*)(qsrc);
        else if (wave < 4) sreg = *(const uint4*)(vsrc);
        if (wave < 2)      *(uint4*)(ql0 + sdst) = sreg;
        else if (wave < 4) *(uint4*)(vl0 + sdst) = sreg;
    }
    __syncthreads();

    const int rdq = ln * 40 + 8 * hi;   // qa0/vb0 ushort offset; +16 for *1
    #pragma unroll 2
    for (int n = 0; n < 32; ++n) {
        const int cur = n & 1;
        // issue next-tile loads early (latency hides under compute)
        uint4 nreg;
        if (n < 31) {
            if (wave < 2)      nreg = *(const uint4*)(qsrc + (n + 1) * 1024);
            else if (wave < 4) nreg = *(const uint4*)(vsrc + (n + 1) * 32);
        }
        // fragments from LDS (shared by all 8 waves)
        const unsigned short* qc = cur ? ql1 : ql0;
        const unsigned short* vc = cur ? vl1 : vl0;
        bf16x8 qa0 = *(const bf16x8*)(qc + rdq);
        bf16x8 qa1 = *(const bf16x8*)(qc + rdq + 16);
        bf16x8 vb0 = *(const bf16x8*)(vc + rdq);
        bf16x8 vb1 = *(const bf16x8*)(vc + rdq + 16);
        // S = Q.K^T (rows q in regs, col a = ln)
        f32x16 s = MFMA32(qa0, kf0, zero16, 0, 0, 0);
        s = MFMA32(qa1, kf1, s, 0, 0, 0);
        // P = exp2(S) -> bf16 pack -> lane-half swap = in-register transpose
        unsigned int w0, w1, w2, w3, w4, w5, w6, w7;
        {
            float p0  = E2(s[0]),  p1  = E2(s[1]),  p2  = E2(s[2]),  p3  = E2(s[3]);
            float p4  = E2(s[4]),  p5  = E2(s[5]),  p6  = E2(s[6]),  p7  = E2(s[7]);
            float p8  = E2(s[8]),  p9  = E2(s[9]),  p10 = E2(s[10]), p11 = E2(s[11]);
            float p12 = E2(s[12]), p13 = E2(s[13]), p14 = E2(s[14]), p15 = E2(s[15]);
            CVTPK(w0, p0,  p1);  CVTPK(w1, p2,  p3);
            CVTPK(w2, p4,  p5);  CVTPK(w3, p6,  p7);
            CVTPK(w4, p8,  p9);  CVTPK(w5, p10, p11);
            CVTPK(w6, p12, p13); CVTPK(w7, p14, p15);
            SWAPH(w0, w2); SWAPH(w1, w3); SWAPH(w4, w6); SWAPH(w5, w7);
        }
        union { uint4 u; bf16x8 v; } pa0, pa1;
        pa0.u = make_uint4(w0, w1, w2, w3);
        pa1.u = make_uint4(w4, w5, w6, w7);
        __builtin_amdgcn_s_setprio(1);
        acc = MFMA32(pa0.v, vb0, acc, 0, 0, 0);
        acc = MFMA32(pa1.v, vb1, acc, 0, 0, 0);
        __builtin_amdgcn_s_setprio(0);
        __syncthreads();
        if (n < 31) {
            unsigned short* qd = cur ? ql0 : ql1;
            unsigned short* vd = cur ? vl0 : vl1;
            if (wave < 2)      *(uint4*)(qd + sdst) = nreg;
            else if (wave < 4) *(uint4*)(vd + sdst) = nreg;
        }
        __syncthreads();
    }

#undef SWAPH
#undef CVTPK

    // D[a][d]: col d = ln, row a = (reg&3) + 8*(reg>>2) + 4*hi
    float* ob = attnT + ((size_t)qh * BB * HID + (size_t)b * HID + h * CH + ln) * LL
                + a0 + 4 * hi;
    *(f32x4*)(ob +  0) = __builtin_shufflevector(acc, acc,  0,  1,  2,  3);
    *(f32x4*)(ob +  8) = __builtin_shufflevector(acc, acc,  4,  5,  6,  7);
    *(f32x4*)(ob + 16) = __builtin_shufflevector(acc, acc,  8,  9, 10, 11);
    *(f32x4*)(ob + 24) = __builtin_shufflevector(acc, acc, 12, 13, 14, 15);
}

// ---------------------------------------------------------------------------
// Kernel 4: out[b,o,l] = BN( w_out @ (sum of 2 f32 partials) + b_out + x )
// ---------------------------------------------------------------------------
__global__ __launch_bounds__(256) void out_kernel(
        const float* __restrict__ attnT, const float* __restrict__ x,
        const float* __restrict__ w_out, const float* __restrict__ b_out,
        const float* __restrict__ bnw, const float* __restrict__ bnb,
        const float* __restrict__ bnm, const float* __restrict__ bnv,
        float* __restrict__ out) {
    __shared__ float wl[8 * 256];
    const int t = threadIdx.x;
    const int l0 = blockIdx.x * 256;
    const int o0 = blockIdx.y * 8;
    const int b  = blockIdx.z;

    const float4* ws = (const float4*)(w_out + (size_t)o0 * HID);
    float4* wd = (float4*)wl;
    #pragma unroll
    for (int r = 0; r < 2; ++r) wd[r * 256 + t] = ws[r * 256 + t];
    __syncthreads();

    float acc[8];
    #pragma unroll
    for (int j = 0; j < 8; ++j) acc[j] = 0.f;

    const size_t PART = (size_t)BB * HID * LL;   // floats per partial
    const float* ap = attnT + (size_t)b * HID * LL + l0 + t;
    for (int i = 0; i < HID; i += 4) {
        const float* p0 = ap + (size_t)(i+0) * LL;
        const float* p1 = ap + (size_t)(i+1) * LL;
        const float* p2 = ap + (size_t)(i+2) * LL;
        const float* p3 = ap + (size_t)(i+3) * LL;
        float a0 = p0[0] + p0[PART];
        float a1 = p1[0] + p1[PART];
        float a2 = p2[0] + p2[PART];
        float a3 = p3[0] + p3[PART];
        #pragma unroll
        for (int j = 0; j < 8; ++j) {
            float4 w4 = *(const float4*)(wl + j * 256 + i);
            acc[j] += w4.x * a0 + w4.y * a1 + w4.z * a2 + w4.w * a3;
        }
    }
    #pragma unroll
    for (int j = 0; j < 8; ++j) {
        const int o = o0 + j;
        const float inv = bnw[o] / sqrtf(bnv[o] + 1e-5f);
        const float sh  = bnb[o] - bnm[o] * inv;
        const size_t idx = ((size_t)b * CIN + o) * LL + l0 + t;
        float val = acc[j] + b_out[o] + x[idx];
        out[idx] = val * inv + sh;
    }
}

// ---------------------------------------------------------------------------
extern "C" void kernel_launch(void* const* d_in, const int* in_sizes, int n_in,
                              void* d_out, int out_size, void* d_ws, size_t ws_size,
                              hipStream_t stream) {
    const float* x      = (const float*)d_in[0];
    const float* w_qkv  = (const float*)d_in[1];
    const float* b_qkv  = (const float*)d_in[2];
    const float* w_out  = (const float*)d_in[3];
    const float* b_out  = (const float*)d_in[4];
    const float* bnw    = (const float*)d_in[5];
    const float* bnb    = (const float*)d_in[6];
    const float* bnm    = (const float*)d_in[7];
    const float* bnv    = (const float*)d_in[8];
    float* out = (float*)d_out;

    const size_t NBH = (size_t)BB * HH;          // 32
    const size_t QKV_ELEMS = NBH * LL * CH;      // 2,097,152 bf16 elems each
    unsigned short* qb    = (unsigned short*)d_ws;
    unsigned short* kb    = qb + QKV_ELEMS;
    unsigned short* vtb   = kb + QKV_ELEMS;
    float* attnT = (float*)(vtb + QKV_ELEMS);    // 2 x 8 MB f32 partials

    qkv_kernel<<<dim3(32, 24, BB), 256, 0, stream>>>(x, w_qkv, b_qkv, qb, kb, vtb);
    denom_mfma<<<dim3(1024), 512, 0, stream>>>(qb, kb, vtb);
    attn_mfma<<<dim3(512), 512, 0, stream>>>(qb, kb, vtb, attnT);
    out_kernel<<<dim3(8, 16, BB), 256, 0, stream>>>(attnT, x, w_out, b_out,
                                                    bnw, bnb, bnm, bnv, out);
}

// Round 13
// 116.450 us; speedup vs baseline: 2.3207x; 1.0976x over previous
//
#include <hip/hip_runtime.h>
#include <math.h>

#define BB 4
#define CIN 128
#define LL 2048
#define HH 8
#define CH 32
#define HID 256

typedef __attribute__((ext_vector_type(8))) __bf16 bf16x8;
typedef __attribute__((ext_vector_type(4))) float f32x4;
typedef __attribute__((ext_vector_type(16))) float f32x16;

static __device__ __forceinline__ unsigned int f2bf(float f) {
    union { __bf16 b; unsigned short s; } u;
    u.b = (__bf16)f;
    return (unsigned int)u.s;
}
static __device__ __forceinline__ float bf2f(unsigned int s) {
    union { float f; unsigned int u; } x;
    x.u = s << 16;
    return x.f;
}

#define MFMA   __builtin_amdgcn_mfma_f32_16x16x32_bf16
#define MFMA32 __builtin_amdgcn_mfma_f32_32x32x16_bf16
#define E2(x)  __builtin_amdgcn_exp2f(x)

// ---------------------------------------------------------------------------
// Kernel 0a: W f32 -> bf16 (layout unchanged [o][i])
// ---------------------------------------------------------------------------
__global__ __launch_bounds__(256) void wconv_kernel(
        const float* __restrict__ w, unsigned short* __restrict__ wb) {
    const int idx = (blockIdx.x * 256 + threadIdx.x) * 4;
    float4 v = *(const float4*)(w + idx);
    uint2 o;
    o.x = f2bf(v.x) | (f2bf(v.y) << 16);
    o.y = f2bf(v.z) | (f2bf(v.w) << 16);
    *(uint2*)(wb + idx) = o;
}

// ---------------------------------------------------------------------------
// Kernel 0b: x [b][i][l] f32 -> xb [b][l][i] bf16 (LDS transpose, coalesced)
// ---------------------------------------------------------------------------
__global__ __launch_bounds__(256) void xpose_kernel(
        const float* __restrict__ x, unsigned short* __restrict__ xb) {
    __shared__ float tr2[128][65];
    const int t = threadIdx.x;
    const int lt = blockIdx.x;   // 0..31 (64-l tile)
    const int b  = blockIdx.y;
    const int l0 = lt * 64;
    const int ll = t & 63, ig = t >> 6;
    const float* xp = x + (size_t)b * CIN * LL + l0 + ll;
    #pragma unroll
    for (int k = 0; k < 32; ++k) {
        const int i = k * 4 + ig;
        tr2[i][ll] = xp[(size_t)i * LL];
    }
    __syncthreads();
    const int l = t >> 2, i0 = (t & 3) * 32;
    unsigned short* dst = xb + ((size_t)b * LL + l0 + l) * CIN + i0;
    unsigned int wv[16];
    #pragma unroll
    for (int j = 0; j < 16; ++j)
        wv[j] = f2bf(tr2[i0 + 2*j][l]) | (f2bf(tr2[i0 + 2*j + 1][l]) << 16);
    *(uint4*)(dst)      = make_uint4(wv[0],  wv[1],  wv[2],  wv[3]);
    *(uint4*)(dst + 8)  = make_uint4(wv[4],  wv[5],  wv[6],  wv[7]);
    *(uint4*)(dst + 16) = make_uint4(wv[8],  wv[9],  wv[10], wv[11]);
    *(uint4*)(dst + 24) = make_uint4(wv[12], wv[13], wv[14], wv[15]);
}

// ---------------------------------------------------------------------------
// Kernel 1: QKV 1x1 conv via bf16 MFMA.  Same grid/epilogue as the proven
// fp32 version; inner product replaced by 8 mfma_16x16x32 per wave.
// Q: [bh][l][d] bf16 pre-scaled by log2(e)/sqrt(L); K: [bh][l][d];
// V: transposed [bh][d][l].
// ---------------------------------------------------------------------------
__global__ __launch_bounds__(256) void qkv_mfma(
        const unsigned short* __restrict__ xb, const unsigned short* __restrict__ wb,
        const float* __restrict__ b_qkv,
        unsigned short* __restrict__ qb, unsigned short* __restrict__ kb,
        unsigned short* __restrict__ vtb) {
    __shared__ float tr[32 * 65];
    const int t = threadIdx.x, w = t >> 6, lane = t & 63;
    const int r = lane & 15, gq = lane >> 4;
    const int lt = blockIdx.x;           // 0..31 (64-l tile)
    const int g  = blockIdx.y;           // 0..23 : sel*8 + h
    const int b  = blockIdx.z;
    const int sel = g >> 3, h = g & 7;
    const int obase = sel * 256 + h * 32;
    const int l0 = lt * 64;

    // A = W rows o (16 per sub-tile), B = x^T cols l (wave w owns l-sub w)
    const unsigned short* wp = wb + ((size_t)(obase + r)) * CIN + gq * 8;
    const unsigned short* xp = xb + ((size_t)b * LL + l0 + w * 16 + r) * CIN + gq * 8;

    f32x4 acc0 = {0,0,0,0}, acc1 = {0,0,0,0};
    #pragma unroll
    for (int ks = 0; ks < 4; ++ks) {
        bf16x8 bfr = *(const bf16x8*)(xp + ks * 32);
        bf16x8 a0  = *(const bf16x8*)(wp + ks * 32);
        bf16x8 a1  = *(const bf16x8*)(wp + 16 * CIN + ks * 32);
        acc0 = MFMA(a0, bfr, acc0, 0, 0, 0);
        acc1 = MFMA(a1, bfr, acc1, 0, 0, 0);
    }
    // D[o][l]: col l = r (lane&15), row o = gq*4 + reg (+16 for acc1)
    const float scale = (sel == 0) ? 0.03187935835f : 1.0f;  // log2(e)/sqrt(2048)
    #pragma unroll
    for (int reg = 0; reg < 4; ++reg) {
        const int oc0 = gq * 4 + reg;
        tr[oc0 * 65 + w * 16 + r] = (acc0[reg] + b_qkv[obase + oc0]) * scale;
        const int oc1 = 16 + gq * 4 + reg;
        tr[oc1 * 65 + w * 16 + r] = (acc1[reg] + b_qkv[obase + oc1]) * scale;
    }
    __syncthreads();

    if (sel == 2) {
        unsigned short* dst = vtb + ((size_t)(b * HH + h) * CH) * LL + l0;
        #pragma unroll
        for (int rr = 0; rr < 8; ++rr) {
            int flat = rr * 256 + t;          // c*64 + l
            int c = flat >> 6, l = flat & 63;
            dst[(size_t)c * LL + l] = (unsigned short)f2bf(tr[c * 65 + l]);
        }
    } else {
        unsigned short* dst = (sel == 0 ? qb : kb)
                              + ((size_t)(b * HH + h) * LL + l0) * CH;
        #pragma unroll
        for (int rr = 0; rr < 8; ++rr) {
            int flat = rr * 256 + t;          // lr*32 + c
            int c = flat & 31, lr = flat >> 5;
            dst[flat] = (unsigned short)f2bf(tr[c * 65 + lr]);
        }
    }
}

// ---------------------------------------------------------------------------
// Kernel 2: softmax denominators via MFMA (K-frag prefetch pipelined), then
// scale V^T in place.  512 threads: waves 0-3 sum a in [0,1024), 4-7 the rest.
// ---------------------------------------------------------------------------
__global__ __launch_bounds__(512) void denom_mfma(
        const unsigned short* __restrict__ qb,
        const unsigned short* __restrict__ kb,
        unsigned short* __restrict__ vtb) {
    __shared__ float zz[2][64];
    const int t = threadIdx.x, wave = t >> 6, lane = t & 63;
    const int id = blockIdx.x;
    const int bh = (id & 7) * 4 + ((id >> 3) >> 5);
    const int qt = (id >> 3) & 31;
    const int ah = wave >> 2, wsub = wave & 3;
    const int q0 = qt * 64 + wsub * 16;
    const int r = lane & 15, g = lane >> 4;

    bf16x8 afrag = *(const bf16x8*)(qb + ((size_t)bh * LL + q0 + r) * CH + 8 * g);
    const unsigned short* kp = kb + ((size_t)bh * LL + ah * 1024 + r) * CH + 8 * g;

    float z0 = 0.f, z1 = 0.f, z2 = 0.f, z3 = 0.f;
    const f32x4 zero = {0.f, 0.f, 0.f, 0.f};
    bf16x8 n0 = *(const bf16x8*)(kp);
    bf16x8 n1 = *(const bf16x8*)(kp + 16 * CH);
    bf16x8 n2 = *(const bf16x8*)(kp + 32 * CH);
    bf16x8 n3 = *(const bf16x8*)(kp + 48 * CH);
    for (int it = 0; it < 16; ++it) {
        bf16x8 c0 = n0, c1 = n1, c2 = n2, c3 = n3;
        if (it < 15) {
            const unsigned short* np = kp + (size_t)(it + 1) * 64 * CH;
            n0 = *(const bf16x8*)(np);
            n1 = *(const bf16x8*)(np + 16 * CH);
            n2 = *(const bf16x8*)(np + 32 * CH);
            n3 = *(const bf16x8*)(np + 48 * CH);
        }
        f32x4 d0 = MFMA(afrag, c0, zero, 0, 0, 0);
        f32x4 d1 = MFMA(afrag, c1, zero, 0, 0, 0);
        f32x4 d2 = MFMA(afrag, c2, zero, 0, 0, 0);
        f32x4 d3 = MFMA(afrag, c3, zero, 0, 0, 0);
        z0 += E2(d0[0]) + E2(d1[0]) + E2(d2[0]) + E2(d3[0]);
        z1 += E2(d0[1]) + E2(d1[1]) + E2(d2[1]) + E2(d3[1]);
        z2 += E2(d0[2]) + E2(d1[2]) + E2(d2[2]) + E2(d3[2]);
        z3 += E2(d0[3]) + E2(d1[3]) + E2(d2[3]) + E2(d3[3]);
    }
    #pragma unroll
    for (int m = 1; m < 16; m <<= 1) {
        z0 += __shfl_xor(z0, m); z1 += __shfl_xor(z1, m);
        z2 += __shfl_xor(z2, m); z3 += __shfl_xor(z3, m);
    }
    if (r == 0) {
        *(float4*)&zz[ah][wsub * 16 + 4 * g] = make_float4(z0, z1, z2, z3);
    }
    __syncthreads();

    const int d = t >> 4, qo = (t & 15) * 4;
    const float i0 = 1.f / (zz[0][qo + 0] + zz[1][qo + 0]);
    const float i1 = 1.f / (zz[0][qo + 1] + zz[1][qo + 1]);
    const float i2 = 1.f / (zz[0][qo + 2] + zz[1][qo + 2]);
    const float i3 = 1.f / (zz[0][qo + 3] + zz[1][qo + 3]);
    unsigned short* vrow = vtb + ((size_t)bh * CH + d) * LL + qt * 64 + qo;
    uint2 v = *(const uint2*)vrow;
    unsigned int w0, w1;
    w0 = f2bf(bf2f(v.x & 0xFFFFu) * i0) | (f2bf(bf2f(v.x >> 16) * i1) << 16);
    w1 = f2bf(bf2f(v.y & 0xFFFFu) * i2) | (f2bf(bf2f(v.y >> 16) * i3) << 16);
    *(uint2*)vrow = make_uint2(w0, w1);
}

// ---------------------------------------------------------------------------
// Kernel 3: attn^T via 32x32x16 MFMA + in-register softmax transpose.
// 8-wave blocks (256 a-cols): Q/V tiles staged once per block into padded
// LDS, shared by all 8 waves (8x fewer L1 line-touches -- R12-proven win).
// ---------------------------------------------------------------------------
__global__ __launch_bounds__(512, 4) void attn_mfma(
        const unsigned short* __restrict__ qb,
        const unsigned short* __restrict__ kb,
        const unsigned short* __restrict__ vtb,
        float* __restrict__ attnT) {
    __shared__ unsigned short qlds[2][32][40];
    __shared__ unsigned short vlds[2][32][40];
    const int t = threadIdx.x, wave = t >> 6, lane = t & 63;
    const int ln = lane & 31, hi = lane >> 5;
    const int id = blockIdx.x;                    // 0..511
    const int bhqh = (id & 7) * 8 + (id >> 6);    // xcd-swizzled (bh,qh)
    const int at = (id >> 3) & 7;
    const int bh = bhqh >> 1, qh = bhqh & 1;
    const int b = bh >> 3, h = bh & 7;
    const int a0 = at * 256 + wave * 32;
    const int q00 = qh * 1024;

    const unsigned short* kp = kb + ((size_t)bh * LL + a0 + ln) * CH + 8 * hi;
    const bf16x8 kf0 = *(const bf16x8*)kp;
    const bf16x8 kf1 = *(const bf16x8*)(kp + 16);

    const int si = t & 127;
    const unsigned short* qsrc = qb + ((size_t)bh * LL + q00) * CH + si * 8;
    const unsigned short* vsrc = vtb + ((size_t)bh * CH + (si >> 2)) * LL
                                 + q00 + (si & 3) * 8;
    const int sdst = (si >> 2) * 40 + (si & 3) * 8;
    unsigned short* const ql0 = &qlds[0][0][0];
    unsigned short* const ql1 = &qlds[1][0][0];
    unsigned short* const vl0 = &vlds[0][0][0];
    unsigned short* const vl1 = &vlds[1][0][0];

    f32x16 acc = {0.f,0.f,0.f,0.f,0.f,0.f,0.f,0.f,0.f,0.f,0.f,0.f,0.f,0.f,0.f,0.f};
    const f32x16 zero16 = {0.f,0.f,0.f,0.f,0.f,0.f,0.f,0.f,0.f,0.f,0.f,0.f,0.f,0.f,0.f,0.f};

#define CVTPK(dst, lo_, hi_) \
    asm("v_cvt_pk_bf16_f32 %0, %1, %2" : "=v"(dst) : "v"(lo_), "v"(hi_))
#define SWAPH(a_, b_) \
    asm("v_permlane32_swap_b32 %0, %1" : "+v"(a_), "+v"(b_))

    {
        uint4 sreg;
        if (wave < 2)      sreg = *(const uint4*)(qsrc);
        else if (wave < 4) sreg = *(const uint4*)(vsrc);
        if (wave < 2)      *(uint4*)(ql0 + sdst) = sreg;
        else if (wave < 4) *(uint4*)(vl0 + sdst) = sreg;
    }
    __syncthreads();

    const int rdq = ln * 40 + 8 * hi;
    #pragma unroll 2
    for (int n = 0; n < 32; ++n) {
        const int cur = n & 1;
        uint4 nreg;
        if (n < 31) {
            if (wave < 2)      nreg = *(const uint4*)(qsrc + (n + 1) * 1024);
            else if (wave < 4) nreg = *(const uint4*)(vsrc + (n + 1) * 32);
        }
        const unsigned short* qc = cur ? ql1 : ql0;
        const unsigned short* vc = cur ? vl1 : vl0;
        bf16x8 qa0 = *(const bf16x8*)(qc + rdq);
        bf16x8 qa1 = *(const bf16x8*)(qc + rdq + 16);
        bf16x8 vb0 = *(const bf16x8*)(vc + rdq);
        bf16x8 vb1 = *(const bf16x8*)(vc + rdq + 16);
        f32x16 s = MFMA32(qa0, kf0, zero16, 0, 0, 0);
        s = MFMA32(qa1, kf1, s, 0, 0, 0);
        unsigned int w0, w1, w2, w3, w4, w5, w6, w7;
        {
            float p0  = E2(s[0]),  p1  = E2(s[1]),  p2  = E2(s[2]),  p3  = E2(s[3]);
            float p4  = E2(s[4]),  p5  = E2(s[5]),  p6  = E2(s[6]),  p7  = E2(s[7]);
            float p8  = E2(s[8]),  p9  = E2(s[9]),  p10 = E2(s[10]), p11 = E2(s[11]);
            float p12 = E2(s[12]), p13 = E2(s[13]), p14 = E2(s[14]), p15 = E2(s[15]);
            CVTPK(w0, p0,  p1);  CVTPK(w1, p2,  p3);
            CVTPK(w2, p4,  p5);  CVTPK(w3, p6,  p7);
            CVTPK(w4, p8,  p9);  CVTPK(w5, p10, p11);
            CVTPK(w6, p12, p13); CVTPK(w7, p14, p15);
            SWAPH(w0, w2); SWAPH(w1, w3); SWAPH(w4, w6); SWAPH(w5, w7);
        }
        union { uint4 u; bf16x8 v; } pa0, pa1;
        pa0.u = make_uint4(w0, w1, w2, w3);
        pa1.u = make_uint4(w4, w5, w6, w7);
        __builtin_amdgcn_s_setprio(1);
        acc = MFMA32(pa0.v, vb0, acc, 0, 0, 0);
        acc = MFMA32(pa1.v, vb1, acc, 0, 0, 0);
        __builtin_amdgcn_s_setprio(0);
        __syncthreads();
        if (n < 31) {
            unsigned short* qd = cur ? ql0 : ql1;
            unsigned short* vd = cur ? vl0 : vl1;
            if (wave < 2)      *(uint4*)(qd + sdst) = nreg;
            else if (wave < 4) *(uint4*)(vd + sdst) = nreg;
        }
        __syncthreads();
    }

#undef SWAPH
#undef CVTPK

    float* ob = attnT + ((size_t)qh * BB * HID + (size_t)b * HID + h * CH + ln) * LL
                + a0 + 4 * hi;
    *(f32x4*)(ob +  0) = __builtin_shufflevector(acc, acc,  0,  1,  2,  3);
    *(f32x4*)(ob +  8) = __builtin_shufflevector(acc, acc,  4,  5,  6,  7);
    *(f32x4*)(ob + 16) = __builtin_shufflevector(acc, acc,  8,  9, 10, 11);
    *(f32x4*)(ob + 24) = __builtin_shufflevector(acc, acc, 12, 13, 14, 15);
}

// ---------------------------------------------------------------------------
// Kernel 4: out[b,o,l] = BN( w_out @ (sum of 2 f32 partials) + b_out + x )
// ---------------------------------------------------------------------------
__global__ __launch_bounds__(256) void out_kernel(
        const float* __restrict__ attnT, const float* __restrict__ x,
        const float* __restrict__ w_out, const float* __restrict__ b_out,
        const float* __restrict__ bnw, const float* __restrict__ bnb,
        const float* __restrict__ bnm, const float* __restrict__ bnv,
        float* __restrict__ out) {
    __shared__ float wl[8 * 256];
    const int t = threadIdx.x;
    const int l0 = blockIdx.x * 256;
    const int o0 = blockIdx.y * 8;
    const int b  = blockIdx.z;

    const float4* ws = (const float4*)(w_out + (size_t)o0 * HID);
    float4* wd = (float4*)wl;
    #pragma unroll
    for (int r = 0; r < 2; ++r) wd[r * 256 + t] = ws[r * 256 + t];
    __syncthreads();

    float acc[8];
    #pragma unroll
    for (int j = 0; j < 8; ++j) acc[j] = 0.f;

    const size_t PART = (size_t)BB * HID * LL;
    const float* ap = attnT + (size_t)b * HID * LL + l0 + t;
    for (int i = 0; i < HID; i += 4) {
        const float* p0 = ap + (size_t)(i+0) * LL;
        const float* p1 = ap + (size_t)(i+1) * LL;
        const float* p2 = ap + (size_t)(i+2) * LL;
        const float* p3 = ap + (size_t)(i+3) * LL;
        float a0 = p0[0] + p0[PART];
        float a1 = p1[0] + p1[PART];
        float a2 = p2[0] + p2[PART];
        float a3 = p3[0] + p3[PART];
        #pragma unroll
        for (int j = 0; j < 8; ++j) {
            float4 w4 = *(const float4*)(wl + j * 256 + i);
            acc[j] += w4.x * a0 + w4.y * a1 + w4.z * a2 + w4.w * a3;
        }
    }
    #pragma unroll
    for (int j = 0; j < 8; ++j) {
        const int o = o0 + j;
        const float inv = bnw[o] / sqrtf(bnv[o] + 1e-5f);
        const float sh  = bnb[o] - bnm[o] * inv;
        const size_t idx = ((size_t)b * CIN + o) * LL + l0 + t;
        float val = acc[j] + b_out[o] + x[idx];
        out[idx] = val * inv + sh;
    }
}

// ---------------------------------------------------------------------------
extern "C" void kernel_launch(void* const* d_in, const int* in_sizes, int n_in,
                              void* d_out, int out_size, void* d_ws, size_t ws_size,
                              hipStream_t stream) {
    const float* x      = (const float*)d_in[0];
    const float* w_qkv  = (const float*)d_in[1];
    const float* b_qkv  = (const float*)d_in[2];
    const float* w_out  = (const float*)d_in[3];
    const float* b_out  = (const float*)d_in[4];
    const float* bnw    = (const float*)d_in[5];
    const float* bnb    = (const float*)d_in[6];
    const float* bnm    = (const float*)d_in[7];
    const float* bnv    = (const float*)d_in[8];
    float* out = (float*)d_out;

    const size_t NBH = (size_t)BB * HH;          // 32
    const size_t QKV_ELEMS = NBH * LL * CH;      // 2,097,152 bf16 elems each
    unsigned short* qb    = (unsigned short*)d_ws;
    unsigned short* kb    = qb + QKV_ELEMS;
    unsigned short* vtb   = kb + QKV_ELEMS;
    float* attnT = (float*)(vtb + QKV_ELEMS);    // 2 x 8 MB f32 partials
    unsigned short* xb = (unsigned short*)(attnT + 2 * (size_t)BB * HID * LL);
    unsigned short* wb = xb + (size_t)BB * LL * CIN;   // 768*128 bf16

    wconv_kernel<<<dim3(96), 256, 0, stream>>>(w_qkv, wb);
    xpose_kernel<<<dim3(32, BB), 256, 0, stream>>>(x, xb);
    qkv_mfma<<<dim3(32, 24, BB), 256, 0, stream>>>(xb, wb, b_qkv, qb, kb, vtb);
    denom_mfma<<<dim3(1024), 512, 0, stream>>>(qb, kb, vtb);
    attn_mfma<<<dim3(512), 512, 0, stream>>>(qb, kb, vtb, attnT);
    out_kernel<<<dim3(8, 16, BB), 256, 0, stream>>>(attnT, x, w_out, b_out,
                                                    bnw, bnb, bnm, bnv, out);
}

// Round 14
// 102.107 us; speedup vs baseline: 2.6467x; 1.1405x over previous
//
#include <hip/hip_runtime.h>
#include <math.h>

#define BB 4
#define CIN 128
#define LL 2048
#define HH 8
#define CH 32
#define HID 256

typedef __attribute__((ext_vector_type(8))) __bf16 bf16x8;
typedef __attribute__((ext_vector_type(4))) float f32x4;
typedef __attribute__((ext_vector_type(16))) float f32x16;

static __device__ __forceinline__ unsigned int f2bf(float f) {
    union { __bf16 b; unsigned short s; } u;
    u.b = (__bf16)f;
    return (unsigned int)u.s;
}
static __device__ __forceinline__ float bf2f(unsigned int s) {
    union { float f; unsigned int u; } x;
    x.u = s << 16;
    return x.f;
}

#define MFMA   __builtin_amdgcn_mfma_f32_16x16x32_bf16
#define MFMA32 __builtin_amdgcn_mfma_f32_32x32x16_bf16
#define E2(x)  __builtin_amdgcn_exp2f(x)

// ---------------------------------------------------------------------------
// Kernel 0 (fused): blocks 0..127: x [b][i][l] f32 -> xb [b][l][i] bf16;
// blocks 128..223: W f32 -> bf16.
// ---------------------------------------------------------------------------
__global__ __launch_bounds__(256) void prep_kernel(
        const float* __restrict__ x, const float* __restrict__ w,
        unsigned short* __restrict__ xb, unsigned short* __restrict__ wb) {
    __shared__ float tr2[128][65];
    const int t = threadIdx.x;
    const int bid = blockIdx.x;
    if (bid >= 128) {
        const int idx = ((bid - 128) * 256 + t) * 4;
        float4 v = *(const float4*)(w + idx);
        uint2 o;
        o.x = f2bf(v.x) | (f2bf(v.y) << 16);
        o.y = f2bf(v.z) | (f2bf(v.w) << 16);
        *(uint2*)(wb + idx) = o;
        return;
    }
    const int lt = bid & 31, b = bid >> 5;
    const int l0 = lt * 64;
    const int ll = t & 63, ig = t >> 6;
    const float* xp = x + (size_t)b * CIN * LL + l0 + ll;
    #pragma unroll
    for (int k = 0; k < 32; ++k) {
        const int i = k * 4 + ig;
        tr2[i][ll] = xp[(size_t)i * LL];
    }
    __syncthreads();
    const int l = t >> 2, i0 = (t & 3) * 32;
    unsigned short* dst = xb + ((size_t)b * LL + l0 + l) * CIN + i0;
    unsigned int wv[16];
    #pragma unroll
    for (int j = 0; j < 16; ++j)
        wv[j] = f2bf(tr2[i0 + 2*j][l]) | (f2bf(tr2[i0 + 2*j + 1][l]) << 16);
    *(uint4*)(dst)      = make_uint4(wv[0],  wv[1],  wv[2],  wv[3]);
    *(uint4*)(dst + 8)  = make_uint4(wv[4],  wv[5],  wv[6],  wv[7]);
    *(uint4*)(dst + 16) = make_uint4(wv[8],  wv[9],  wv[10], wv[11]);
    *(uint4*)(dst + 24) = make_uint4(wv[12], wv[13], wv[14], wv[15]);
}

// ---------------------------------------------------------------------------
// Kernel 1: QKV 1x1 conv via bf16 MFMA (R13-proven).
// Q: [bh][l][d] bf16 pre-scaled by log2(e)/sqrt(L); K: [bh][l][d];
// V: transposed [bh][d][l].
// ---------------------------------------------------------------------------
__global__ __launch_bounds__(256) void qkv_mfma(
        const unsigned short* __restrict__ xb, const unsigned short* __restrict__ wb,
        const float* __restrict__ b_qkv,
        unsigned short* __restrict__ qb, unsigned short* __restrict__ kb,
        unsigned short* __restrict__ vtb) {
    __shared__ float tr[32 * 65];
    const int t = threadIdx.x, w = t >> 6, lane = t & 63;
    const int r = lane & 15, gq = lane >> 4;
    const int lt = blockIdx.x;           // 0..31 (64-l tile)
    const int g  = blockIdx.y;           // 0..23 : sel*8 + h
    const int b  = blockIdx.z;
    const int sel = g >> 3, h = g & 7;
    const int obase = sel * 256 + h * 32;
    const int l0 = lt * 64;

    const unsigned short* wp = wb + ((size_t)(obase + r)) * CIN + gq * 8;
    const unsigned short* xp = xb + ((size_t)b * LL + l0 + w * 16 + r) * CIN + gq * 8;

    f32x4 acc0 = {0,0,0,0}, acc1 = {0,0,0,0};
    #pragma unroll
    for (int ks = 0; ks < 4; ++ks) {
        bf16x8 bfr = *(const bf16x8*)(xp + ks * 32);
        bf16x8 a0  = *(const bf16x8*)(wp + ks * 32);
        bf16x8 a1  = *(const bf16x8*)(wp + 16 * CIN + ks * 32);
        acc0 = MFMA(a0, bfr, acc0, 0, 0, 0);
        acc1 = MFMA(a1, bfr, acc1, 0, 0, 0);
    }
    const float scale = (sel == 0) ? 0.03187935835f : 1.0f;  // log2(e)/sqrt(2048)
    #pragma unroll
    for (int reg = 0; reg < 4; ++reg) {
        const int oc0 = gq * 4 + reg;
        tr[oc0 * 65 + w * 16 + r] = (acc0[reg] + b_qkv[obase + oc0]) * scale;
        const int oc1 = 16 + gq * 4 + reg;
        tr[oc1 * 65 + w * 16 + r] = (acc1[reg] + b_qkv[obase + oc1]) * scale;
    }
    __syncthreads();

    if (sel == 2) {
        unsigned short* dst = vtb + ((size_t)(b * HH + h) * CH) * LL + l0;
        #pragma unroll
        for (int rr = 0; rr < 8; ++rr) {
            int flat = rr * 256 + t;
            int c = flat >> 6, l = flat & 63;
            dst[(size_t)c * LL + l] = (unsigned short)f2bf(tr[c * 65 + l]);
        }
    } else {
        unsigned short* dst = (sel == 0 ? qb : kb)
                              + ((size_t)(b * HH + h) * LL + l0) * CH;
        #pragma unroll
        for (int rr = 0; rr < 8; ++rr) {
            int flat = rr * 256 + t;
            int c = flat & 31, lr = flat >> 5;
            dst[flat] = (unsigned short)f2bf(tr[c * 65 + lr]);
        }
    }
}

// ---------------------------------------------------------------------------
// Kernel 2: softmax denominators, LDS-staged K (R12-proven mechanism).
// Block = (bh, 128-q tile), 8 waves; wave owns 16 q over the FULL a-range.
// K chunk (64 a x 32 d = 4KB) staged once per block, double-buffered,
// shared by all 8 waves -> 8x fewer K line-touches.  Then scale V^T.
// ---------------------------------------------------------------------------
__global__ __launch_bounds__(512, 4) void denom_mfma(
        const unsigned short* __restrict__ qb,
        const unsigned short* __restrict__ kb,
        unsigned short* __restrict__ vtb) {
    __shared__ unsigned short klds[2][64][40];
    __shared__ float zz[128];
    const int t = threadIdx.x, wave = t >> 6, lane = t & 63;
    const int id = blockIdx.x;                 // 0..511
    const int bh = (id & 7) * 4 + (id >> 7);   // xcd-swizzled
    const int qt = (id >> 3) & 15;             // 128-q tile
    const int r = lane & 15, g = lane >> 4;
    const int q0 = qt * 128 + wave * 16;

    bf16x8 afrag = *(const bf16x8*)(qb + ((size_t)bh * LL + q0 + r) * CH + 8 * g);

    // staging (threads < 256): contiguous 16B/lane, 4KB/chunk
    const int si = t;
    const unsigned short* ksrc = kb + (size_t)bh * LL * CH + si * 8;  // chunk 0
    const int sdst = (si >> 2) * 40 + (si & 3) * 8;

    float z0 = 0.f, z1 = 0.f, z2 = 0.f, z3 = 0.f;
    const f32x4 zero = {0.f, 0.f, 0.f, 0.f};

    if (t < 256) {
        uint4 sreg = *(const uint4*)(ksrc);
        *(uint4*)(&klds[0][0][0] + sdst) = sreg;
    }
    __syncthreads();

    const int rb = r * 40 + 8 * g;
    for (int c = 0; c < 32; ++c) {
        const int cur = c & 1;
        uint4 nreg;
        if (c < 31 && t < 256)
            nreg = *(const uint4*)(ksrc + (size_t)(c + 1) * 2048);
        const unsigned short* kc = &klds[cur][0][0];
        #pragma unroll
        for (int s = 0; s < 4; ++s) {
            bf16x8 bf = *(const bf16x8*)(kc + s * 16 * 40 + rb);
            f32x4 d = MFMA(afrag, bf, zero, 0, 0, 0);
            z0 += E2(d[0]); z1 += E2(d[1]); z2 += E2(d[2]); z3 += E2(d[3]);
        }
        __syncthreads();
        if (c < 31 && t < 256)
            *(uint4*)(&klds[cur ^ 1][0][0] + sdst) = nreg;
        __syncthreads();
    }

    #pragma unroll
    for (int m = 1; m < 16; m <<= 1) {
        z0 += __shfl_xor(z0, m); z1 += __shfl_xor(z1, m);
        z2 += __shfl_xor(z2, m); z3 += __shfl_xor(z3, m);
    }
    if (r == 0)
        *(float4*)&zz[wave * 16 + 4 * g] = make_float4(z0, z1, z2, z3);
    __syncthreads();
    if (t < 128) zz[t] = 1.0f / zz[t];
    __syncthreads();

    // scale vtb[bh][d][qt*128 .. +127]: 512 thr x 8 elems = 32 d x 128 q
    const int d = t >> 4, qo = (t & 15) * 8;
    unsigned short* vrow = vtb + ((size_t)bh * CH + d) * LL + qt * 128 + qo;
    uint4 v = *(const uint4*)vrow;
    const float* zp = &zz[qo];
    unsigned int w0, w1, w2, w3;
    w0 = f2bf(bf2f(v.x & 0xFFFFu) * zp[0]) | (f2bf(bf2f(v.x >> 16) * zp[1]) << 16);
    w1 = f2bf(bf2f(v.y & 0xFFFFu) * zp[2]) | (f2bf(bf2f(v.y >> 16) * zp[3]) << 16);
    w2 = f2bf(bf2f(v.z & 0xFFFFu) * zp[4]) | (f2bf(bf2f(v.z >> 16) * zp[5]) << 16);
    w3 = f2bf(bf2f(v.w & 0xFFFFu) * zp[6]) | (f2bf(bf2f(v.w >> 16) * zp[7]) << 16);
    *(uint4*)vrow = make_uint4(w0, w1, w2, w3);
}

// ---------------------------------------------------------------------------
// Kernel 3: attn^T via 32x32x16 MFMA + in-register softmax transpose
// (R12-proven).  8-wave blocks; Q/V tiles staged once per block into padded
// LDS, shared by all 8 waves.
// ---------------------------------------------------------------------------
__global__ __launch_bounds__(512, 4) void attn_mfma(
        const unsigned short* __restrict__ qb,
        const unsigned short* __restrict__ kb,
        const unsigned short* __restrict__ vtb,
        float* __restrict__ attnT) {
    __shared__ unsigned short qlds[2][32][40];
    __shared__ unsigned short vlds[2][32][40];
    const int t = threadIdx.x, wave = t >> 6, lane = t & 63;
    const int ln = lane & 31, hi = lane >> 5;
    const int id = blockIdx.x;                    // 0..511
    const int bhqh = (id & 7) * 8 + (id >> 6);    // xcd-swizzled (bh,qh)
    const int at = (id >> 3) & 7;
    const int bh = bhqh >> 1, qh = bhqh & 1;
    const int b = bh >> 3, h = bh & 7;
    const int a0 = at * 256 + wave * 32;
    const int q00 = qh * 1024;

    const unsigned short* kp = kb + ((size_t)bh * LL + a0 + ln) * CH + 8 * hi;
    const bf16x8 kf0 = *(const bf16x8*)kp;
    const bf16x8 kf1 = *(const bf16x8*)(kp + 16);

    const int si = t & 127;
    const unsigned short* qsrc = qb + ((size_t)bh * LL + q00) * CH + si * 8;
    const unsigned short* vsrc = vtb + ((size_t)bh * CH + (si >> 2)) * LL
                                 + q00 + (si & 3) * 8;
    const int sdst = (si >> 2) * 40 + (si & 3) * 8;
    unsigned short* const ql0 = &qlds[0][0][0];
    unsigned short* const ql1 = &qlds[1][0][0];
    unsigned short* const vl0 = &vlds[0][0][0];
    unsigned short* const vl1 = &vlds[1][0][0];

    f32x16 acc = {0.f,0.f,0.f,0.f,0.f,0.f,0.f,0.f,0.f,0.f,0.f,0.f,0.f,0.f,0.f,0.f};
    const f32x16 zero16 = {0.f,0.f,0.f,0.f,0.f,0.f,0.f,0.f,0.f,0.f,0.f,0.f,0.f,0.f,0.f,0.f};

#define CVTPK(dst, lo_, hi_) \
    asm("v_cvt_pk_bf16_f32 %0, %1, %2" : "=v"(dst) : "v"(lo_), "v"(hi_))
#define SWAPH(a_, b_) \
    asm("v_permlane32_swap_b32 %0, %1" : "+v"(a_), "+v"(b_))

    {
        uint4 sreg;
        if (wave < 2)      sreg = *(const uint4*)(qsrc);
        else if (wave < 4) sreg = *(const uint4*)(vsrc);
        if (wave < 2)      *(uint4*)(ql0 + sdst) = sreg;
        else if (wave < 4) *(uint4*)(vl0 + sdst) = sreg;
    }
    __syncthreads();

    const int rdq = ln * 40 + 8 * hi;
    #pragma unroll 2
    for (int n = 0; n < 32; ++n) {
        const int cur = n & 1;
        uint4 nreg;
        if (n < 31) {
            if (wave < 2)      nreg = *(const uint4*)(qsrc + (n + 1) * 1024);
            else if (wave < 4) nreg = *(const uint4*)(vsrc + (n + 1) * 32);
        }
        const unsigned short* qc = cur ? ql1 : ql0;
        const unsigned short* vc = cur ? vl1 : vl0;
        bf16x8 qa0 = *(const bf16x8*)(qc + rdq);
        bf16x8 qa1 = *(const bf16x8*)(qc + rdq + 16);
        bf16x8 vb0 = *(const bf16x8*)(vc + rdq);
        bf16x8 vb1 = *(const bf16x8*)(vc + rdq + 16);
        f32x16 s = MFMA32(qa0, kf0, zero16, 0, 0, 0);
        s = MFMA32(qa1, kf1, s, 0, 0, 0);
        unsigned int w0, w1, w2, w3, w4, w5, w6, w7;
        {
            float p0  = E2(s[0]),  p1  = E2(s[1]),  p2  = E2(s[2]),  p3  = E2(s[3]);
            float p4  = E2(s[4]),  p5  = E2(s[5]),  p6  = E2(s[6]),  p7  = E2(s[7]);
            float p8  = E2(s[8]),  p9  = E2(s[9]),  p10 = E2(s[10]), p11 = E2(s[11]);
            float p12 = E2(s[12]), p13 = E2(s[13]), p14 = E2(s[14]), p15 = E2(s[15]);
            CVTPK(w0, p0,  p1);  CVTPK(w1, p2,  p3);
            CVTPK(w2, p4,  p5);  CVTPK(w3, p6,  p7);
            CVTPK(w4, p8,  p9);  CVTPK(w5, p10, p11);
            CVTPK(w6, p12, p13); CVTPK(w7, p14, p15);
            SWAPH(w0, w2); SWAPH(w1, w3); SWAPH(w4, w6); SWAPH(w5, w7);
        }
        union { uint4 u; bf16x8 v; } pa0, pa1;
        pa0.u = make_uint4(w0, w1, w2, w3);
        pa1.u = make_uint4(w4, w5, w6, w7);
        __builtin_amdgcn_s_setprio(1);
        acc = MFMA32(pa0.v, vb0, acc, 0, 0, 0);
        acc = MFMA32(pa1.v, vb1, acc, 0, 0, 0);
        __builtin_amdgcn_s_setprio(0);
        __syncthreads();
        if (n < 31) {
            unsigned short* qd = cur ? ql0 : ql1;
            unsigned short* vd = cur ? vl0 : vl1;
            if (wave < 2)      *(uint4*)(qd + sdst) = nreg;
            else if (wave < 4) *(uint4*)(vd + sdst) = nreg;
        }
        __syncthreads();
    }

#undef SWAPH
#undef CVTPK

    float* ob = attnT + ((size_t)qh * BB * HID + (size_t)b * HID + h * CH + ln) * LL
                + a0 + 4 * hi;
    *(f32x4*)(ob +  0) = __builtin_shufflevector(acc, acc,  0,  1,  2,  3);
    *(f32x4*)(ob +  8) = __builtin_shufflevector(acc, acc,  4,  5,  6,  7);
    *(f32x4*)(ob + 16) = __builtin_shufflevector(acc, acc,  8,  9, 10, 11);
    *(f32x4*)(ob + 24) = __builtin_shufflevector(acc, acc, 12, 13, 14, 15);
}

// ---------------------------------------------------------------------------
// Kernel 4: out[b,o,l] = BN( w_out @ (sum of 2 f32 partials) + b_out + x )
// ---------------------------------------------------------------------------
__global__ __launch_bounds__(256) void out_kernel(
        const float* __restrict__ attnT, const float* __restrict__ x,
        const float* __restrict__ w_out, const float* __restrict__ b_out,
        const float* __restrict__ bnw, const float* __restrict__ bnb,
        const float* __restrict__ bnm, const float* __restrict__ bnv,
        float* __restrict__ out) {
    __shared__ float wl[8 * 256];
    const int t = threadIdx.x;
    const int l0 = blockIdx.x * 256;
    const int o0 = blockIdx.y * 8;
    const int b  = blockIdx.z;

    const float4* ws = (const float4*)(w_out + (size_t)o0 * HID);
    float4* wd = (float4*)wl;
    #pragma unroll
    for (int r = 0; r < 2; ++r) wd[r * 256 + t] = ws[r * 256 + t];
    __syncthreads();

    float acc[8];
    #pragma unroll
    for (int j = 0; j < 8; ++j) acc[j] = 0.f;

    const size_t PART = (size_t)BB * HID * LL;
    const float* ap = attnT + (size_t)b * HID * LL + l0 + t;
    for (int i = 0; i < HID; i += 4) {
        const float* p0 = ap + (size_t)(i+0) * LL;
        const float* p1 = ap + (size_t)(i+1) * LL;
        const float* p2 = ap + (size_t)(i+2) * LL;
        const float* p3 = ap + (size_t)(i+3) * LL;
        float a0 = p0[0] + p0[PART];
        float a1 = p1[0] + p1[PART];
        float a2 = p2[0] + p2[PART];
        float a3 = p3[0] + p3[PART];
        #pragma unroll
        for (int j = 0; j < 8; ++j) {
            float4 w4 = *(const float4*)(wl + j * 256 + i);
            acc[j] += w4.x * a0 + w4.y * a1 + w4.z * a2 + w4.w * a3;
        }
    }
    #pragma unroll
    for (int j = 0; j < 8; ++j) {
        const int o = o0 + j;
        const float inv = bnw[o] / sqrtf(bnv[o] + 1e-5f);
        const float sh  = bnb[o] - bnm[o] * inv;
        const size_t idx = ((size_t)b * CIN + o) * LL + l0 + t;
        float val = acc[j] + b_out[o] + x[idx];
        out[idx] = val * inv + sh;
    }
}

// ---------------------------------------------------------------------------
extern "C" void kernel_launch(void* const* d_in, const int* in_sizes, int n_in,
                              void* d_out, int out_size, void* d_ws, size_t ws_size,
                              hipStream_t stream) {
    const float* x      = (const float*)d_in[0];
    const float* w_qkv  = (const float*)d_in[1];
    const float* b_qkv  = (const float*)d_in[2];
    const float* w_out  = (const float*)d_in[3];
    const float* b_out  = (const float*)d_in[4];
    const float* bnw    = (const float*)d_in[5];
    const float* bnb    = (const float*)d_in[6];
    const float* bnm    = (const float*)d_in[7];
    const float* bnv    = (const float*)d_in[8];
    float* out = (float*)d_out;

    const size_t NBH = (size_t)BB * HH;          // 32
    const size_t QKV_ELEMS = NBH * LL * CH;      // 2,097,152 bf16 elems each
    unsigned short* qb    = (unsigned short*)d_ws;
    unsigned short* kb    = qb + QKV_ELEMS;
    unsigned short* vtb   = kb + QKV_ELEMS;
    float* attnT = (float*)(vtb + QKV_ELEMS);    // 2 x 8 MB f32 partials
    unsigned short* xb = (unsigned short*)(attnT + 2 * (size_t)BB * HID * LL);
    unsigned short* wb = xb + (size_t)BB * LL * CIN;   // 768*128 bf16

    prep_kernel<<<dim3(224), 256, 0, stream>>>(x, w_qkv, xb, wb);
    qkv_mfma<<<dim3(32, 24, BB), 256, 0, stream>>>(xb, wb, b_qkv, qb, kb, vtb);
    denom_mfma<<<dim3(512), 512, 0, stream>>>(qb, kb, vtb);
    attn_mfma<<<dim3(512), 512, 0, stream>>>(qb, kb, vtb, attnT);
    out_kernel<<<dim3(8, 16, BB), 256, 0, stream>>>(attnT, x, w_out, b_out,
                                                    bnw, bnb, bnm, bnv, out);
}

// Round 15
// 75.465 us; speedup vs baseline: 3.5811x; 1.3530x over previous
//
#include <hip/hip_runtime.h>
#include <math.h>

#define BB 4
#define CIN 128
#define LL 2048
#define HH 8
#define CH 32
#define HID 256

typedef __attribute__((ext_vector_type(8))) __bf16 bf16x8;
typedef __attribute__((ext_vector_type(4))) float f32x4;
typedef __attribute__((ext_vector_type(16))) float f32x16;

static __device__ __forceinline__ unsigned int f2bf(float f) {
    union { __bf16 b; unsigned short s; } u;
    u.b = (__bf16)f;
    return (unsigned int)u.s;
}
static __device__ __forceinline__ float bf2f(unsigned int s) {
    union { float f; unsigned int u; } x;
    x.u = s << 16;
    return x.f;
}

#define MFMA   __builtin_amdgcn_mfma_f32_16x16x32_bf16
#define MFMA32 __builtin_amdgcn_mfma_f32_32x32x16_bf16
#define E2(x)  __builtin_amdgcn_exp2f(x)

// ---------------------------------------------------------------------------
// Kernel 0 (fused): blocks 0..127: x -> x^T bf16; 128..223: w_qkv -> bf16;
// 224..255: w_out -> bf16.
// ---------------------------------------------------------------------------
__global__ __launch_bounds__(256) void prep_kernel(
        const float* __restrict__ x, const float* __restrict__ w,
        const float* __restrict__ wo,
        unsigned short* __restrict__ xb, unsigned short* __restrict__ wb,
        unsigned short* __restrict__ wob) {
    __shared__ float tr2[128][65];
    const int t = threadIdx.x;
    const int bid = blockIdx.x;
    if (bid >= 224) {
        const int idx = ((bid - 224) * 256 + t) * 4;
        float4 v = *(const float4*)(wo + idx);
        uint2 o;
        o.x = f2bf(v.x) | (f2bf(v.y) << 16);
        o.y = f2bf(v.z) | (f2bf(v.w) << 16);
        *(uint2*)(wob + idx) = o;
        return;
    }
    if (bid >= 128) {
        const int idx = ((bid - 128) * 256 + t) * 4;
        float4 v = *(const float4*)(w + idx);
        uint2 o;
        o.x = f2bf(v.x) | (f2bf(v.y) << 16);
        o.y = f2bf(v.z) | (f2bf(v.w) << 16);
        *(uint2*)(wb + idx) = o;
        return;
    }
    const int lt = bid & 31, b = bid >> 5;
    const int l0 = lt * 64;
    const int ll = t & 63, ig = t >> 6;
    const float* xp = x + (size_t)b * CIN * LL + l0 + ll;
    #pragma unroll
    for (int k = 0; k < 32; ++k) {
        const int i = k * 4 + ig;
        tr2[i][ll] = xp[(size_t)i * LL];
    }
    __syncthreads();
    const int l = t >> 2, i0 = (t & 3) * 32;
    unsigned short* dst = xb + ((size_t)b * LL + l0 + l) * CIN + i0;
    unsigned int wv[16];
    #pragma unroll
    for (int j = 0; j < 16; ++j)
        wv[j] = f2bf(tr2[i0 + 2*j][l]) | (f2bf(tr2[i0 + 2*j + 1][l]) << 16);
    *(uint4*)(dst)      = make_uint4(wv[0],  wv[1],  wv[2],  wv[3]);
    *(uint4*)(dst + 8)  = make_uint4(wv[4],  wv[5],  wv[6],  wv[7]);
    *(uint4*)(dst + 16) = make_uint4(wv[8],  wv[9],  wv[10], wv[11]);
    *(uint4*)(dst + 24) = make_uint4(wv[12], wv[13], wv[14], wv[15]);
}

// ---------------------------------------------------------------------------
// Kernel 1: QKV via bf16 MFMA, LDS-staged x-tile and W-slice (contiguous
// staging loads; fragments from LDS -> no 256B-stride line-touch storm).
// ---------------------------------------------------------------------------
__global__ __launch_bounds__(256) void qkv_mfma(
        const unsigned short* __restrict__ xb, const unsigned short* __restrict__ wb,
        const float* __restrict__ b_qkv,
        unsigned short* __restrict__ qb, unsigned short* __restrict__ kb,
        unsigned short* __restrict__ vtb) {
    __shared__ unsigned short xlds[64][136];   // [l][i], stride 272B (16B-align, 2-way)
    __shared__ unsigned short wlds2[32][136];  // [o][i]
    __shared__ float tr[32 * 65];
    const int t = threadIdx.x, w = t >> 6, lane = t & 63;
    const int r = lane & 15, gq = lane >> 4;
    const int lt = blockIdx.x;           // 0..31 (64-l tile)
    const int g  = blockIdx.y;           // 0..23 : sel*8 + h
    const int b  = blockIdx.z;
    const int sel = g >> 3, h = g & 7;
    const int obase = sel * 256 + h * 32;
    const int l0 = lt * 64;

    {
        const unsigned short* xsrc = xb + ((size_t)b * LL + l0) * CIN;
        #pragma unroll
        for (int k2 = 0; k2 < 4; ++k2) {
            int idx = t + k2 * 256;              // 0..1023
            int row = idx >> 4, col8 = (idx & 15) * 8;
            *(uint4*)&xlds[row][col8] = *(const uint4*)(xsrc + row * CIN + col8);
        }
        const unsigned short* wsrc = wb + (size_t)obase * CIN;
        #pragma unroll
        for (int k2 = 0; k2 < 2; ++k2) {
            int idx = t + k2 * 256;              // 0..511
            int row = idx >> 4, col8 = (idx & 15) * 8;
            *(uint4*)&wlds2[row][col8] = *(const uint4*)(wsrc + row * CIN + col8);
        }
    }
    __syncthreads();

    f32x4 acc0 = {0,0,0,0}, acc1 = {0,0,0,0};
    #pragma unroll
    for (int ks = 0; ks < 4; ++ks) {
        bf16x8 bfr = *(const bf16x8*)&xlds[w * 16 + r][gq * 8 + ks * 32];
        bf16x8 a0  = *(const bf16x8*)&wlds2[r][gq * 8 + ks * 32];
        bf16x8 a1  = *(const bf16x8*)&wlds2[16 + r][gq * 8 + ks * 32];
        acc0 = MFMA(a0, bfr, acc0, 0, 0, 0);
        acc1 = MFMA(a1, bfr, acc1, 0, 0, 0);
    }
    const float scale = (sel == 0) ? 0.03187935835f : 1.0f;  // log2(e)/sqrt(2048)
    #pragma unroll
    for (int reg = 0; reg < 4; ++reg) {
        const int oc0 = gq * 4 + reg;
        tr[oc0 * 65 + w * 16 + r] = (acc0[reg] + b_qkv[obase + oc0]) * scale;
        const int oc1 = 16 + gq * 4 + reg;
        tr[oc1 * 65 + w * 16 + r] = (acc1[reg] + b_qkv[obase + oc1]) * scale;
    }
    __syncthreads();

    if (sel == 2) {
        unsigned short* dst = vtb + ((size_t)(b * HH + h) * CH) * LL + l0;
        #pragma unroll
        for (int rr = 0; rr < 8; ++rr) {
            int flat = rr * 256 + t;
            int c = flat >> 6, l = flat & 63;
            dst[(size_t)c * LL + l] = (unsigned short)f2bf(tr[c * 65 + l]);
        }
    } else {
        unsigned short* dst = (sel == 0 ? qb : kb)
                              + ((size_t)(b * HH + h) * LL + l0) * CH;
        #pragma unroll
        for (int rr = 0; rr < 8; ++rr) {
            int flat = rr * 256 + t;
            int c = flat & 31, lr = flat >> 5;
            dst[flat] = (unsigned short)f2bf(tr[c * 65 + lr]);
        }
    }
}

// ---------------------------------------------------------------------------
// Kernel 2: softmax denominators, LDS-staged K (R14-proven).
// ---------------------------------------------------------------------------
__global__ __launch_bounds__(512, 4) void denom_mfma(
        const unsigned short* __restrict__ qb,
        const unsigned short* __restrict__ kb,
        unsigned short* __restrict__ vtb) {
    __shared__ unsigned short klds[2][64][40];
    __shared__ float zz[128];
    const int t = threadIdx.x, wave = t >> 6, lane = t & 63;
    const int id = blockIdx.x;                 // 0..511
    const int bh = (id & 7) * 4 + (id >> 7);   // xcd-swizzled
    const int qt = (id >> 3) & 15;             // 128-q tile
    const int r = lane & 15, g = lane >> 4;
    const int q0 = qt * 128 + wave * 16;

    bf16x8 afrag = *(const bf16x8*)(qb + ((size_t)bh * LL + q0 + r) * CH + 8 * g);

    const int si = t;
    const unsigned short* ksrc = kb + (size_t)bh * LL * CH + si * 8;
    const int sdst = (si >> 2) * 40 + (si & 3) * 8;

    float z0 = 0.f, z1 = 0.f, z2 = 0.f, z3 = 0.f;
    const f32x4 zero = {0.f, 0.f, 0.f, 0.f};

    if (t < 256) {
        uint4 sreg = *(const uint4*)(ksrc);
        *(uint4*)(&klds[0][0][0] + sdst) = sreg;
    }
    __syncthreads();

    const int rb = r * 40 + 8 * g;
    for (int c = 0; c < 32; ++c) {
        const int cur = c & 1;
        uint4 nreg;
        if (c < 31 && t < 256)
            nreg = *(const uint4*)(ksrc + (size_t)(c + 1) * 2048);
        const unsigned short* kc = &klds[cur][0][0];
        #pragma unroll
        for (int s = 0; s < 4; ++s) {
            bf16x8 bf = *(const bf16x8*)(kc + s * 16 * 40 + rb);
            f32x4 d = MFMA(afrag, bf, zero, 0, 0, 0);
            z0 += E2(d[0]); z1 += E2(d[1]); z2 += E2(d[2]); z3 += E2(d[3]);
        }
        __syncthreads();
        if (c < 31 && t < 256)
            *(uint4*)(&klds[cur ^ 1][0][0] + sdst) = nreg;
        __syncthreads();
    }

    #pragma unroll
    for (int m = 1; m < 16; m <<= 1) {
        z0 += __shfl_xor(z0, m); z1 += __shfl_xor(z1, m);
        z2 += __shfl_xor(z2, m); z3 += __shfl_xor(z3, m);
    }
    if (r == 0)
        *(float4*)&zz[wave * 16 + 4 * g] = make_float4(z0, z1, z2, z3);
    __syncthreads();
    if (t < 128) zz[t] = 1.0f / zz[t];
    __syncthreads();

    const int d = t >> 4, qo = (t & 15) * 8;
    unsigned short* vrow = vtb + ((size_t)bh * CH + d) * LL + qt * 128 + qo;
    uint4 v = *(const uint4*)vrow;
    const float* zp = &zz[qo];
    unsigned int w0, w1, w2, w3;
    w0 = f2bf(bf2f(v.x & 0xFFFFu) * zp[0]) | (f2bf(bf2f(v.x >> 16) * zp[1]) << 16);
    w1 = f2bf(bf2f(v.y & 0xFFFFu) * zp[2]) | (f2bf(bf2f(v.y >> 16) * zp[3]) << 16);
    w2 = f2bf(bf2f(v.z & 0xFFFFu) * zp[4]) | (f2bf(bf2f(v.z >> 16) * zp[5]) << 16);
    w3 = f2bf(bf2f(v.w & 0xFFFFu) * zp[6]) | (f2bf(bf2f(v.w >> 16) * zp[7]) << 16);
    *(uint4*)vrow = make_uint4(w0, w1, w2, w3);
}

// ---------------------------------------------------------------------------
// Kernel 3: attn^T via 32x32x16 MFMA + in-register softmax transpose
// (R12-proven).
// ---------------------------------------------------------------------------
__global__ __launch_bounds__(512, 4) void attn_mfma(
        const unsigned short* __restrict__ qb,
        const unsigned short* __restrict__ kb,
        const unsigned short* __restrict__ vtb,
        float* __restrict__ attnT) {
    __shared__ unsigned short qlds[2][32][40];
    __shared__ unsigned short vlds[2][32][40];
    const int t = threadIdx.x, wave = t >> 6, lane = t & 63;
    const int ln = lane & 31, hi = lane >> 5;
    const int id = blockIdx.x;                    // 0..511
    const int bhqh = (id & 7) * 8 + (id >> 6);    // xcd-swizzled (bh,qh)
    const int at = (id >> 3) & 7;
    const int bh = bhqh >> 1, qh = bhqh & 1;
    const int b = bh >> 3, h = bh & 7;
    const int a0 = at * 256 + wave * 32;
    const int q00 = qh * 1024;

    const unsigned short* kp = kb + ((size_t)bh * LL + a0 + ln) * CH + 8 * hi;
    const bf16x8 kf0 = *(const bf16x8*)kp;
    const bf16x8 kf1 = *(const bf16x8*)(kp + 16);

    const int si = t & 127;
    const unsigned short* qsrc = qb + ((size_t)bh * LL + q00) * CH + si * 8;
    const unsigned short* vsrc = vtb + ((size_t)bh * CH + (si >> 2)) * LL
                                 + q00 + (si & 3) * 8;
    const int sdst = (si >> 2) * 40 + (si & 3) * 8;
    unsigned short* const ql0 = &qlds[0][0][0];
    unsigned short* const ql1 = &qlds[1][0][0];
    unsigned short* const vl0 = &vlds[0][0][0];
    unsigned short* const vl1 = &vlds[1][0][0];

    f32x16 acc = {0.f,0.f,0.f,0.f,0.f,0.f,0.f,0.f,0.f,0.f,0.f,0.f,0.f,0.f,0.f,0.f};
    const f32x16 zero16 = {0.f,0.f,0.f,0.f,0.f,0.f,0.f,0.f,0.f,0.f,0.f,0.f,0.f,0.f,0.f,0.f};

#define CVTPK(dst, lo_, hi_) \
    asm("v_cvt_pk_bf16_f32 %0, %1, %2" : "=v"(dst) : "v"(lo_), "v"(hi_))
#define SWAPH(a_, b_) \
    asm("v_permlane32_swap_b32 %0, %1" : "+v"(a_), "+v"(b_))

    {
        uint4 sreg;
        if (wave < 2)      sreg = *(const uint4*)(qsrc);
        else if (wave < 4) sreg = *(const uint4*)(vsrc);
        if (wave < 2)      *(uint4*)(ql0 + sdst) = sreg;
        else if (wave < 4) *(uint4*)(vl0 + sdst) = sreg;
    }
    __syncthreads();

    const int rdq = ln * 40 + 8 * hi;
    #pragma unroll 2
    for (int n = 0; n < 32; ++n) {
        const int cur = n & 1;
        uint4 nreg;
        if (n < 31) {
            if (wave < 2)      nreg = *(const uint4*)(qsrc + (n + 1) * 1024);
            else if (wave < 4) nreg = *(const uint4*)(vsrc + (n + 1) * 32);
        }
        const unsigned short* qc = cur ? ql1 : ql0;
        const unsigned short* vc = cur ? vl1 : vl0;
        bf16x8 qa0 = *(const bf16x8*)(qc + rdq);
        bf16x8 qa1 = *(const bf16x8*)(qc + rdq + 16);
        bf16x8 vb0 = *(const bf16x8*)(vc + rdq);
        bf16x8 vb1 = *(const bf16x8*)(vc + rdq + 16);
        f32x16 s = MFMA32(qa0, kf0, zero16, 0, 0, 0);
        s = MFMA32(qa1, kf1, s, 0, 0, 0);
        unsigned int w0, w1, w2, w3, w4, w5, w6, w7;
        {
            float p0  = E2(s[0]),  p1  = E2(s[1]),  p2  = E2(s[2]),  p3  = E2(s[3]);
            float p4  = E2(s[4]),  p5  = E2(s[5]),  p6  = E2(s[6]),  p7  = E2(s[7]);
            float p8  = E2(s[8]),  p9  = E2(s[9]),  p10 = E2(s[10]), p11 = E2(s[11]);
            float p12 = E2(s[12]), p13 = E2(s[13]), p14 = E2(s[14]), p15 = E2(s[15]);
            CVTPK(w0, p0,  p1);  CVTPK(w1, p2,  p3);
            CVTPK(w2, p4,  p5);  CVTPK(w3, p6,  p7);
            CVTPK(w4, p8,  p9);  CVTPK(w5, p10, p11);
            CVTPK(w6, p12, p13); CVTPK(w7, p14, p15);
            SWAPH(w0, w2); SWAPH(w1, w3); SWAPH(w4, w6); SWAPH(w5, w7);
        }
        union { uint4 u; bf16x8 v; } pa0, pa1;
        pa0.u = make_uint4(w0, w1, w2, w3);
        pa1.u = make_uint4(w4, w5, w6, w7);
        __builtin_amdgcn_s_setprio(1);
        acc = MFMA32(pa0.v, vb0, acc, 0, 0, 0);
        acc = MFMA32(pa1.v, vb1, acc, 0, 0, 0);
        __builtin_amdgcn_s_setprio(0);
        __syncthreads();
        if (n < 31) {
            unsigned short* qd = cur ? ql0 : ql1;
            unsigned short* vd = cur ? vl0 : vl1;
            if (wave < 2)      *(uint4*)(qd + sdst) = nreg;
            else if (wave < 4) *(uint4*)(vd + sdst) = nreg;
        }
        __syncthreads();
    }

#undef SWAPH
#undef CVTPK

    float* ob = attnT + ((size_t)qh * BB * HID + (size_t)b * HID + h * CH + ln) * LL
                + a0 + 4 * hi;
    *(f32x4*)(ob +  0) = __builtin_shufflevector(acc, acc,  0,  1,  2,  3);
    *(f32x4*)(ob +  8) = __builtin_shufflevector(acc, acc,  4,  5,  6,  7);
    *(f32x4*)(ob + 16) = __builtin_shufflevector(acc, acc,  8,  9, 10, 11);
    *(f32x4*)(ob + 24) = __builtin_shufflevector(acc, acc, 12, 13, 14, 15);
}

// ---------------------------------------------------------------------------
// Kernel 4: out projection via MFMA GEMM.  D[o][l] = W[o][i] @ A[i][l];
// A = sum of 2 f32 partials, converted to bf16 at staging time.
// Block: (b, 32-l tile), 4 waves = 4 o-subtiles of 32.  attnT read ONCE.
// Epilogue: bias + residual + BN.
// ---------------------------------------------------------------------------
__global__ __launch_bounds__(256, 4) void out_mfma(
        const float* __restrict__ attnT, const unsigned short* __restrict__ wob,
        const float* __restrict__ x, const float* __restrict__ b_out,
        const float* __restrict__ bnw, const float* __restrict__ bnb,
        const float* __restrict__ bnm, const float* __restrict__ bnv,
        float* __restrict__ out) {
    __shared__ unsigned short alds[2][32][40];    // [l][i] bf16
    __shared__ unsigned short wlds[2][128][40];   // [o][i] bf16
    const int t = threadIdx.x, wave = t >> 6, lane = t & 63;
    const int ln = lane & 31, hi = lane >> 5;
    const int id = blockIdx.x;                    // 0..255
    const int bid = (id & 7) * 32 + (id >> 3);    // xcd swizzle (256 = 8*32)
    const int b = bid >> 6, lt = bid & 63;
    const int l0 = lt * 32;
    const size_t PART = (size_t)BB * HID * LL;

    // staging: alds: thread -> (i = t>>3, 4 l's); wlds: 2 rows per thread
    const int si = t >> 3, sl4 = (t & 7) * 4;
    const float* ap0 = attnT + ((size_t)b * HID + si) * LL + l0 + sl4;
    const unsigned short* wsrc0 = wob + (size_t)(t >> 2) * HID + (t & 3) * 8;
    const unsigned short* wsrc1 = wsrc0 + (size_t)64 * HID;
    unsigned short* const wdst0 = &wlds[0][t >> 2][(t & 3) * 8];
    const int WBUF = 128 * 40;                    // ushorts per wlds buffer

    f32x16 acc = {0.f,0.f,0.f,0.f,0.f,0.f,0.f,0.f,0.f,0.f,0.f,0.f,0.f,0.f,0.f,0.f};

    // prologue: stage chunk 0 into buf 0
    {
        f32x4 a0 = *(const f32x4*)(ap0);
        f32x4 a1 = *(const f32x4*)(ap0 + PART);
        uint4 w0 = *(const uint4*)(wsrc0);
        uint4 w1 = *(const uint4*)(wsrc1);
        #pragma unroll
        for (int j = 0; j < 4; ++j)
            alds[0][sl4 + j][si] = (unsigned short)f2bf(a0[j] + a1[j]);
        *(uint4*)(wdst0) = w0;
        *(uint4*)(wdst0 + 64 * 40) = w1;
    }
    __syncthreads();

    for (int c = 0; c < 8; ++c) {
        const int cur = c & 1;
        f32x4 na0, na1; uint4 nw0, nw1;
        if (c < 7) {
            na0 = *(const f32x4*)(ap0 + (size_t)(c + 1) * 32 * LL);
            na1 = *(const f32x4*)(ap0 + (size_t)(c + 1) * 32 * LL + PART);
            nw0 = *(const uint4*)(wsrc0 + (c + 1) * 32);
            nw1 = *(const uint4*)(wsrc1 + (c + 1) * 32);
        }
        // fragments
        const unsigned short* wc = &wlds[cur][0][0] + (wave * 32 + ln) * 40 + 8 * hi;
        const unsigned short* ac = &alds[cur][0][0] + ln * 40 + 8 * hi;
        bf16x8 af0 = *(const bf16x8*)(wc);
        bf16x8 af1 = *(const bf16x8*)(wc + 16);
        bf16x8 bf0 = *(const bf16x8*)(ac);
        bf16x8 bf1 = *(const bf16x8*)(ac + 16);
        acc = MFMA32(af0, bf0, acc, 0, 0, 0);
        acc = MFMA32(af1, bf1, acc, 0, 0, 0);
        __syncthreads();
        if (c < 7) {
            const int nb = cur ^ 1;
            #pragma unroll
            for (int j = 0; j < 4; ++j)
                alds[nb][sl4 + j][si] = (unsigned short)f2bf(na0[j] + na1[j]);
            *(uint4*)(wdst0 + nb * 2 * WBUF / 2) = nw0;              // wlds[nb]
            *(uint4*)(wdst0 + nb * 2 * WBUF / 2 + 64 * 40) = nw1;
        }
        __syncthreads();
    }

    // epilogue: D[o][l]: col l = ln, row o = wave*32 + (reg&3)+8*(reg>>2)+4*hi
    #pragma unroll
    for (int reg = 0; reg < 16; ++reg) {
        const int o = wave * 32 + (reg & 3) + 8 * (reg >> 2) + 4 * hi;
        const float inv = bnw[o] / sqrtf(bnv[o] + 1e-5f);
        const float sh  = bnb[o] - bnm[o] * inv;
        const size_t idx = ((size_t)b * CIN + o) * LL + l0 + ln;
        float val = acc[reg] + b_out[o] + x[idx];
        out[idx] = val * inv + sh;
    }
}

// ---------------------------------------------------------------------------
extern "C" void kernel_launch(void* const* d_in, const int* in_sizes, int n_in,
                              void* d_out, int out_size, void* d_ws, size_t ws_size,
                              hipStream_t stream) {
    const float* x      = (const float*)d_in[0];
    const float* w_qkv  = (const float*)d_in[1];
    const float* b_qkv  = (const float*)d_in[2];
    const float* w_out  = (const float*)d_in[3];
    const float* b_out  = (const float*)d_in[4];
    const float* bnw    = (const float*)d_in[5];
    const float* bnb    = (const float*)d_in[6];
    const float* bnm    = (const float*)d_in[7];
    const float* bnv    = (const float*)d_in[8];
    float* out = (float*)d_out;

    const size_t NBH = (size_t)BB * HH;          // 32
    const size_t QKV_ELEMS = NBH * LL * CH;      // 2,097,152 bf16 elems each
    unsigned short* qb    = (unsigned short*)d_ws;
    unsigned short* kb    = qb + QKV_ELEMS;
    unsigned short* vtb   = kb + QKV_ELEMS;
    float* attnT = (float*)(vtb + QKV_ELEMS);    // 2 x 8 MB f32 partials
    unsigned short* xb  = (unsigned short*)(attnT + 2 * (size_t)BB * HID * LL);
    unsigned short* wb  = xb + (size_t)BB * LL * CIN;   // 768*128 bf16
    unsigned short* wob = wb + (size_t)3 * HID * CIN;   // 128*256 bf16

    prep_kernel<<<dim3(256), 256, 0, stream>>>(x, w_qkv, w_out, xb, wb, wob);
    qkv_mfma<<<dim3(32, 24, BB), 256, 0, stream>>>(xb, wb, b_qkv, qb, kb, vtb);
    denom_mfma<<<dim3(512), 512, 0, stream>>>(qb, kb, vtb);
    attn_mfma<<<dim3(512), 512, 0, stream>>>(qb, kb, vtb, attnT);
    out_mfma<<<dim3(256), 256, 0, stream>>>(attnT, wob, x, b_out,
                                            bnw, bnb, bnm, bnv, out);
}

// Round 16
// 71.177 us; speedup vs baseline: 3.7968x; 1.0602x over previous
//
#include <hip/hip_runtime.h>
#include <math.h>

#define BB 4
#define CIN 128
#define LL 2048
#define HH 8
#define CH 32
#define HID 256

typedef __attribute__((ext_vector_type(8))) __bf16 bf16x8;
typedef __attribute__((ext_vector_type(4))) float f32x4;
typedef __attribute__((ext_vector_type(16))) float f32x16;

static __device__ __forceinline__ unsigned int f2bf(float f) {
    union { __bf16 b; unsigned short s; } u;
    u.b = (__bf16)f;
    return (unsigned int)u.s;
}
static __device__ __forceinline__ float bf2f(unsigned int s) {
    union { float f; unsigned int u; } x;
    x.u = s << 16;
    return x.f;
}

#define MFMA   __builtin_amdgcn_mfma_f32_16x16x32_bf16
#define MFMA32 __builtin_amdgcn_mfma_f32_32x32x16_bf16
#define E2(x)  __builtin_amdgcn_exp2f(x)

// ---------------------------------------------------------------------------
// Kernel 0 (fused): blocks 0..127: x -> x^T bf16; 128..223: w_qkv -> bf16;
// 224..255: w_out -> bf16.
// ---------------------------------------------------------------------------
__global__ __launch_bounds__(256) void prep_kernel(
        const float* __restrict__ x, const float* __restrict__ w,
        const float* __restrict__ wo,
        unsigned short* __restrict__ xb, unsigned short* __restrict__ wb,
        unsigned short* __restrict__ wob) {
    __shared__ float tr2[128][65];
    const int t = threadIdx.x;
    const int bid = blockIdx.x;
    if (bid >= 224) {
        const int idx = ((bid - 224) * 256 + t) * 4;
        float4 v = *(const float4*)(wo + idx);
        uint2 o;
        o.x = f2bf(v.x) | (f2bf(v.y) << 16);
        o.y = f2bf(v.z) | (f2bf(v.w) << 16);
        *(uint2*)(wob + idx) = o;
        return;
    }
    if (bid >= 128) {
        const int idx = ((bid - 128) * 256 + t) * 4;
        float4 v = *(const float4*)(w + idx);
        uint2 o;
        o.x = f2bf(v.x) | (f2bf(v.y) << 16);
        o.y = f2bf(v.z) | (f2bf(v.w) << 16);
        *(uint2*)(wb + idx) = o;
        return;
    }
    const int lt = bid & 31, b = bid >> 5;
    const int l0 = lt * 64;
    const int ll = t & 63, ig = t >> 6;
    const float* xp = x + (size_t)b * CIN * LL + l0 + ll;
    #pragma unroll
    for (int k = 0; k < 32; ++k) {
        const int i = k * 4 + ig;
        tr2[i][ll] = xp[(size_t)i * LL];
    }
    __syncthreads();
    const int l = t >> 2, i0 = (t & 3) * 32;
    unsigned short* dst = xb + ((size_t)b * LL + l0 + l) * CIN + i0;
    unsigned int wv[16];
    #pragma unroll
    for (int j = 0; j < 16; ++j)
        wv[j] = f2bf(tr2[i0 + 2*j][l]) | (f2bf(tr2[i0 + 2*j + 1][l]) << 16);
    *(uint4*)(dst)      = make_uint4(wv[0],  wv[1],  wv[2],  wv[3]);
    *(uint4*)(dst + 8)  = make_uint4(wv[4],  wv[5],  wv[6],  wv[7]);
    *(uint4*)(dst + 16) = make_uint4(wv[8],  wv[9],  wv[10], wv[11]);
    *(uint4*)(dst + 24) = make_uint4(wv[12], wv[13], wv[14], wv[15]);
}

// ---------------------------------------------------------------------------
// Kernel 1: QKV via bf16 MFMA, LDS-staged x-tile and W-slice (R15-proven).
// ---------------------------------------------------------------------------
__global__ __launch_bounds__(256) void qkv_mfma(
        const unsigned short* __restrict__ xb, const unsigned short* __restrict__ wb,
        const float* __restrict__ b_qkv,
        unsigned short* __restrict__ qb, unsigned short* __restrict__ kb,
        unsigned short* __restrict__ vtb) {
    __shared__ unsigned short xlds[64][136];
    __shared__ unsigned short wlds2[32][136];
    __shared__ float tr[32 * 65];
    const int t = threadIdx.x, w = t >> 6, lane = t & 63;
    const int r = lane & 15, gq = lane >> 4;
    const int lt = blockIdx.x;           // 0..31 (64-l tile)
    const int g  = blockIdx.y;           // 0..23 : sel*8 + h
    const int b  = blockIdx.z;
    const int sel = g >> 3, h = g & 7;
    const int obase = sel * 256 + h * 32;
    const int l0 = lt * 64;

    {
        const unsigned short* xsrc = xb + ((size_t)b * LL + l0) * CIN;
        #pragma unroll
        for (int k2 = 0; k2 < 4; ++k2) {
            int idx = t + k2 * 256;
            int row = idx >> 4, col8 = (idx & 15) * 8;
            *(uint4*)&xlds[row][col8] = *(const uint4*)(xsrc + row * CIN + col8);
        }
        const unsigned short* wsrc = wb + (size_t)obase * CIN;
        #pragma unroll
        for (int k2 = 0; k2 < 2; ++k2) {
            int idx = t + k2 * 256;
            int row = idx >> 4, col8 = (idx & 15) * 8;
            *(uint4*)&wlds2[row][col8] = *(const uint4*)(wsrc + row * CIN + col8);
        }
    }
    __syncthreads();

    f32x4 acc0 = {0,0,0,0}, acc1 = {0,0,0,0};
    #pragma unroll
    for (int ks = 0; ks < 4; ++ks) {
        bf16x8 bfr = *(const bf16x8*)&xlds[w * 16 + r][gq * 8 + ks * 32];
        bf16x8 a0  = *(const bf16x8*)&wlds2[r][gq * 8 + ks * 32];
        bf16x8 a1  = *(const bf16x8*)&wlds2[16 + r][gq * 8 + ks * 32];
        acc0 = MFMA(a0, bfr, acc0, 0, 0, 0);
        acc1 = MFMA(a1, bfr, acc1, 0, 0, 0);
    }
    const float scale = (sel == 0) ? 0.03187935835f : 1.0f;  // log2(e)/sqrt(2048)
    #pragma unroll
    for (int reg = 0; reg < 4; ++reg) {
        const int oc0 = gq * 4 + reg;
        tr[oc0 * 65 + w * 16 + r] = (acc0[reg] + b_qkv[obase + oc0]) * scale;
        const int oc1 = 16 + gq * 4 + reg;
        tr[oc1 * 65 + w * 16 + r] = (acc1[reg] + b_qkv[obase + oc1]) * scale;
    }
    __syncthreads();

    if (sel == 2) {
        unsigned short* dst = vtb + ((size_t)(b * HH + h) * CH) * LL + l0;
        #pragma unroll
        for (int rr = 0; rr < 8; ++rr) {
            int flat = rr * 256 + t;
            int c = flat >> 6, l = flat & 63;
            dst[(size_t)c * LL + l] = (unsigned short)f2bf(tr[c * 65 + l]);
        }
    } else {
        unsigned short* dst = (sel == 0 ? qb : kb)
                              + ((size_t)(b * HH + h) * LL + l0) * CH;
        #pragma unroll
        for (int rr = 0; rr < 8; ++rr) {
            int flat = rr * 256 + t;
            int c = flat & 31, lr = flat >> 5;
            dst[flat] = (unsigned short)f2bf(tr[c * 65 + lr]);
        }
    }
}

// ---------------------------------------------------------------------------
// Kernel 2: softmax denominators, LDS-staged K.  R16: 128-a chunks staged by
// ALL 512 threads, ONE barrier per chunk (double-buffer protocol needs only
// the end-of-iteration barrier).  Then scale V^T in place.
// ---------------------------------------------------------------------------
__global__ __launch_bounds__(512, 4) void denom_mfma(
        const unsigned short* __restrict__ qb,
        const unsigned short* __restrict__ kb,
        unsigned short* __restrict__ vtb) {
    __shared__ unsigned short klds[2][128][40];
    __shared__ float zz[128];
    const int t = threadIdx.x, wave = t >> 6, lane = t & 63;
    const int id = blockIdx.x;                 // 0..511
    const int bh = (id & 7) * 4 + (id >> 7);   // xcd-swizzled
    const int qt = (id >> 3) & 15;             // 128-q tile
    const int r = lane & 15, g = lane >> 4;
    const int q0 = qt * 128 + wave * 16;

    bf16x8 afrag = *(const bf16x8*)(qb + ((size_t)bh * LL + q0 + r) * CH + 8 * g);

    // staging: all 512 threads, 16B each -> 8KB chunk (128 a x 32 d)
    const unsigned short* ksrc = kb + ((size_t)bh * LL + (t >> 2)) * CH + (t & 3) * 8;
    const int sdst = (t >> 2) * 40 + (t & 3) * 8;

    float z0 = 0.f, z1 = 0.f, z2 = 0.f, z3 = 0.f;
    const f32x4 zero = {0.f, 0.f, 0.f, 0.f};

    *(uint4*)(&klds[0][0][0] + sdst) = *(const uint4*)(ksrc);
    __syncthreads();

    const int rb = r * 40 + 8 * g;
    for (int c = 0; c < 16; ++c) {
        const int cur = c & 1;
        uint4 nreg;
        if (c < 15)
            nreg = *(const uint4*)(ksrc + (size_t)(c + 1) * 4096);
        const unsigned short* kc = &klds[cur][0][0];
        #pragma unroll
        for (int s = 0; s < 8; ++s) {
            bf16x8 bf = *(const bf16x8*)(kc + s * 16 * 40 + rb);
            f32x4 d = MFMA(afrag, bf, zero, 0, 0, 0);
            z0 += E2(d[0]); z1 += E2(d[1]); z2 += E2(d[2]); z3 += E2(d[3]);
        }
        if (c < 15)
            *(uint4*)(&klds[cur ^ 1][0][0] + sdst) = nreg;
        __syncthreads();
    }

    #pragma unroll
    for (int m = 1; m < 16; m <<= 1) {
        z0 += __shfl_xor(z0, m); z1 += __shfl_xor(z1, m);
        z2 += __shfl_xor(z2, m); z3 += __shfl_xor(z3, m);
    }
    if (r == 0)
        *(float4*)&zz[wave * 16 + 4 * g] = make_float4(z0, z1, z2, z3);
    __syncthreads();
    if (t < 128) zz[t] = 1.0f / zz[t];
    __syncthreads();

    const int d = t >> 4, qo = (t & 15) * 8;
    unsigned short* vrow = vtb + ((size_t)bh * CH + d) * LL + qt * 128 + qo;
    uint4 v = *(const uint4*)vrow;
    const float* zp = &zz[qo];
    unsigned int w0, w1, w2, w3;
    w0 = f2bf(bf2f(v.x & 0xFFFFu) * zp[0]) | (f2bf(bf2f(v.x >> 16) * zp[1]) << 16);
    w1 = f2bf(bf2f(v.y & 0xFFFFu) * zp[2]) | (f2bf(bf2f(v.y >> 16) * zp[3]) << 16);
    w2 = f2bf(bf2f(v.z & 0xFFFFu) * zp[4]) | (f2bf(bf2f(v.z >> 16) * zp[5]) << 16);
    w3 = f2bf(bf2f(v.w & 0xFFFFu) * zp[6]) | (f2bf(bf2f(v.w >> 16) * zp[7]) << 16);
    *(uint4*)vrow = make_uint4(w0, w1, w2, w3);
}

// ---------------------------------------------------------------------------
// Kernel 3: attn^T via 32x32x16 MFMA + in-register softmax transpose.
// R16: 64-q chunks (16 iters), ONE barrier per iter, all 8 waves stage
// (waves 0-3: Q chunk 4KB; waves 4-7: V chunk 4KB).
// ---------------------------------------------------------------------------
__global__ __launch_bounds__(512, 4) void attn_mfma(
        const unsigned short* __restrict__ qb,
        const unsigned short* __restrict__ kb,
        const unsigned short* __restrict__ vtb,
        float* __restrict__ attnT) {
    __shared__ unsigned short qlds[2][64][40];   // [q][d]
    __shared__ unsigned short vlds[2][64][40];   // [sub*32+d][q]
    const int t = threadIdx.x, wave = t >> 6, lane = t & 63;
    const int ln = lane & 31, hi = lane >> 5;
    const int id = blockIdx.x;                    // 0..511
    const int bhqh = (id & 7) * 8 + (id >> 6);    // xcd-swizzled (bh,qh)
    const int at = (id >> 3) & 7;
    const int bh = bhqh >> 1, qh = bhqh & 1;
    const int b = bh >> 3, h = bh & 7;
    const int a0 = at * 256 + wave * 32;
    const int q00 = qh * 1024;

    const unsigned short* kp = kb + ((size_t)bh * LL + a0 + ln) * CH + 8 * hi;
    const bf16x8 kf0 = *(const bf16x8*)kp;
    const bf16x8 kf1 = *(const bf16x8*)(kp + 16);

    // staging addresses
    const int ts = t & 255;
    const unsigned short* qsrc = qb + ((size_t)bh * LL + q00 + (ts >> 2)) * CH
                                 + (ts & 3) * 8;                       // waves 0-3
    const int vsub = ts >> 7, vd = (ts >> 2) & 31, vq = (ts & 3) * 8;
    const unsigned short* vsrc = vtb + ((size_t)bh * CH + vd) * LL + q00
                                 + vsub * 32 + vq;                     // waves 4-7
    const int sdstq = (ts >> 2) * 40 + (ts & 3) * 8;
    const int sdstv = (vsub * 32 + vd) * 40 + vq;
    unsigned short* const ql0 = &qlds[0][0][0];
    unsigned short* const ql1 = &qlds[1][0][0];
    unsigned short* const vl0 = &vlds[0][0][0];
    unsigned short* const vl1 = &vlds[1][0][0];

    f32x16 acc = {0.f,0.f,0.f,0.f,0.f,0.f,0.f,0.f,0.f,0.f,0.f,0.f,0.f,0.f,0.f,0.f};
    const f32x16 zero16 = {0.f,0.f,0.f,0.f,0.f,0.f,0.f,0.f,0.f,0.f,0.f,0.f,0.f,0.f,0.f,0.f};

#define CVTPK(dst, lo_, hi_) \
    asm("v_cvt_pk_bf16_f32 %0, %1, %2" : "=v"(dst) : "v"(lo_), "v"(hi_))
#define SWAPH(a_, b_) \
    asm("v_permlane32_swap_b32 %0, %1" : "+v"(a_), "+v"(b_))

    // prologue: stage chunk 0 into buf 0
    if (wave < 4) *(uint4*)(ql0 + sdstq) = *(const uint4*)(qsrc);
    else          *(uint4*)(vl0 + sdstv) = *(const uint4*)(vsrc);
    __syncthreads();

    for (int n = 0; n < 16; ++n) {
        const int cur = n & 1;
        uint4 nreg;
        if (n < 15) {
            if (wave < 4) nreg = *(const uint4*)(qsrc + (size_t)(n + 1) * 2048);
            else          nreg = *(const uint4*)(vsrc + (n + 1) * 64);
        }
        const unsigned short* qc = cur ? ql1 : ql0;
        const unsigned short* vc = cur ? vl1 : vl0;
        #pragma unroll
        for (int s2 = 0; s2 < 2; ++s2) {
            const int rdq = (s2 * 32 + ln) * 40 + 8 * hi;
            bf16x8 qa0 = *(const bf16x8*)(qc + rdq);
            bf16x8 qa1 = *(const bf16x8*)(qc + rdq + 16);
            bf16x8 vb0 = *(const bf16x8*)(vc + rdq);
            bf16x8 vb1 = *(const bf16x8*)(vc + rdq + 16);
            f32x16 s = MFMA32(qa0, kf0, zero16, 0, 0, 0);
            s = MFMA32(qa1, kf1, s, 0, 0, 0);
            unsigned int w0, w1, w2, w3, w4, w5, w6, w7;
            {
                float p0  = E2(s[0]),  p1  = E2(s[1]),  p2  = E2(s[2]),  p3  = E2(s[3]);
                float p4  = E2(s[4]),  p5  = E2(s[5]),  p6  = E2(s[6]),  p7  = E2(s[7]);
                float p8  = E2(s[8]),  p9  = E2(s[9]),  p10 = E2(s[10]), p11 = E2(s[11]);
                float p12 = E2(s[12]), p13 = E2(s[13]), p14 = E2(s[14]), p15 = E2(s[15]);
                CVTPK(w0, p0,  p1);  CVTPK(w1, p2,  p3);
                CVTPK(w2, p4,  p5);  CVTPK(w3, p6,  p7);
                CVTPK(w4, p8,  p9);  CVTPK(w5, p10, p11);
                CVTPK(w6, p12, p13); CVTPK(w7, p14, p15);
                SWAPH(w0, w2); SWAPH(w1, w3); SWAPH(w4, w6); SWAPH(w5, w7);
            }
            union { uint4 u; bf16x8 v; } pa0, pa1;
            pa0.u = make_uint4(w0, w1, w2, w3);
            pa1.u = make_uint4(w4, w5, w6, w7);
            __builtin_amdgcn_s_setprio(1);
            acc = MFMA32(pa0.v, vb0, acc, 0, 0, 0);
            acc = MFMA32(pa1.v, vb1, acc, 0, 0, 0);
            __builtin_amdgcn_s_setprio(0);
        }
        if (n < 15) {
            if (wave < 4) *(uint4*)((cur ? ql0 : ql1) + sdstq) = nreg;
            else          *(uint4*)((cur ? vl0 : vl1) + sdstv) = nreg;
        }
        __syncthreads();
    }

#undef SWAPH
#undef CVTPK

    float* ob = attnT + ((size_t)qh * BB * HID + (size_t)b * HID + h * CH + ln) * LL
                + a0 + 4 * hi;
    *(f32x4*)(ob +  0) = __builtin_shufflevector(acc, acc,  0,  1,  2,  3);
    *(f32x4*)(ob +  8) = __builtin_shufflevector(acc, acc,  4,  5,  6,  7);
    *(f32x4*)(ob + 16) = __builtin_shufflevector(acc, acc,  8,  9, 10, 11);
    *(f32x4*)(ob + 24) = __builtin_shufflevector(acc, acc, 12, 13, 14, 15);
}

// ---------------------------------------------------------------------------
// Kernel 4: out projection via MFMA GEMM (R15-proven), one barrier per chunk.
// ---------------------------------------------------------------------------
__global__ __launch_bounds__(256, 4) void out_mfma(
        const float* __restrict__ attnT, const unsigned short* __restrict__ wob,
        const float* __restrict__ x, const float* __restrict__ b_out,
        const float* __restrict__ bnw, const float* __restrict__ bnb,
        const float* __restrict__ bnm, const float* __restrict__ bnv,
        float* __restrict__ out) {
    __shared__ unsigned short alds[2][32][40];    // [l][i] bf16
    __shared__ unsigned short wlds[2][128][40];   // [o][i] bf16
    const int t = threadIdx.x, wave = t >> 6, lane = t & 63;
    const int ln = lane & 31, hi = lane >> 5;
    const int id = blockIdx.x;                    // 0..255
    const int bid = (id & 7) * 32 + (id >> 3);    // xcd swizzle
    const int b = bid >> 6, lt = bid & 63;
    const int l0 = lt * 32;
    const size_t PART = (size_t)BB * HID * LL;
    const int WBUF = 128 * 40;

    const int si = t >> 3, sl4 = (t & 7) * 4;
    const float* ap0 = attnT + ((size_t)b * HID + si) * LL + l0 + sl4;
    const unsigned short* wsrc0 = wob + (size_t)(t >> 2) * HID + (t & 3) * 8;
    const unsigned short* wsrc1 = wsrc0 + (size_t)64 * HID;
    unsigned short* const wdst0 = &wlds[0][t >> 2][(t & 3) * 8];

    f32x16 acc = {0.f,0.f,0.f,0.f,0.f,0.f,0.f,0.f,0.f,0.f,0.f,0.f,0.f,0.f,0.f,0.f};

    {
        f32x4 a0 = *(const f32x4*)(ap0);
        f32x4 a1 = *(const f32x4*)(ap0 + PART);
        uint4 w0 = *(const uint4*)(wsrc0);
        uint4 w1 = *(const uint4*)(wsrc1);
        #pragma unroll
        for (int j = 0; j < 4; ++j)
            alds[0][sl4 + j][si] = (unsigned short)f2bf(a0[j] + a1[j]);
        *(uint4*)(wdst0) = w0;
        *(uint4*)(wdst0 + 64 * 40) = w1;
    }
    __syncthreads();

    for (int c = 0; c < 8; ++c) {
        const int cur = c & 1;
        f32x4 na0, na1; uint4 nw0, nw1;
        if (c < 7) {
            na0 = *(const f32x4*)(ap0 + (size_t)(c + 1) * 32 * LL);
            na1 = *(const f32x4*)(ap0 + (size_t)(c + 1) * 32 * LL + PART);
            nw0 = *(const uint4*)(wsrc0 + (c + 1) * 32);
            nw1 = *(const uint4*)(wsrc1 + (c + 1) * 32);
        }
        const unsigned short* wc = &wlds[cur][0][0] + (wave * 32 + ln) * 40 + 8 * hi;
        const unsigned short* ac = &alds[cur][0][0] + ln * 40 + 8 * hi;
        bf16x8 af0 = *(const bf16x8*)(wc);
        bf16x8 af1 = *(const bf16x8*)(wc + 16);
        bf16x8 bf0 = *(const bf16x8*)(ac);
        bf16x8 bf1 = *(const bf16x8*)(ac + 16);
        acc = MFMA32(af0, bf0, acc, 0, 0, 0);
        acc = MFMA32(af1, bf1, acc, 0, 0, 0);
        if (c < 7) {
            const int nb = cur ^ 1;
            #pragma unroll
            for (int j = 0; j < 4; ++j)
                alds[nb][sl4 + j][si] = (unsigned short)f2bf(na0[j] + na1[j]);
            *(uint4*)(wdst0 + nb * WBUF) = nw0;
            *(uint4*)(wdst0 + nb * WBUF + 64 * 40) = nw1;
        }
        __syncthreads();
    }

    #pragma unroll
    for (int reg = 0; reg < 16; ++reg) {
        const int o = wave * 32 + (reg & 3) + 8 * (reg >> 2) + 4 * hi;
        const float inv = bnw[o] / sqrtf(bnv[o] + 1e-5f);
        const float sh  = bnb[o] - bnm[o] * inv;
        const size_t idx = ((size_t)b * CIN + o) * LL + l0 + ln;
        float val = acc[reg] + b_out[o] + x[idx];
        out[idx] = val * inv + sh;
    }
}

// ---------------------------------------------------------------------------
extern "C" void kernel_launch(void* const* d_in, const int* in_sizes, int n_in,
                              void* d_out, int out_size, void* d_ws, size_t ws_size,
                              hipStream_t stream) {
    const float* x      = (const float*)d_in[0];
    const float* w_qkv  = (const float*)d_in[1];
    const float* b_qkv  = (const float*)d_in[2];
    const float* w_out  = (const float*)d_in[3];
    const float* b_out  = (const float*)d_in[4];
    const float* bnw    = (const float*)d_in[5];
    const float* bnb    = (const float*)d_in[6];
    const float* bnm    = (const float*)d_in[7];
    const float* bnv    = (const float*)d_in[8];
    float* out = (float*)d_out;

    const size_t NBH = (size_t)BB * HH;          // 32
    const size_t QKV_ELEMS = NBH * LL * CH;      // 2,097,152 bf16 elems each
    unsigned short* qb    = (unsigned short*)d_ws;
    unsigned short* kb    = qb + QKV_ELEMS;
    unsigned short* vtb   = kb + QKV_ELEMS;
    float* attnT = (float*)(vtb + QKV_ELEMS);    // 2 x 8 MB f32 partials
    unsigned short* xb  = (unsigned short*)(attnT + 2 * (size_t)BB * HID * LL);
    unsigned short* wb  = xb + (size_t)BB * LL * CIN;   // 768*128 bf16
    unsigned short* wob = wb + (size_t)3 * HID * CIN;   // 128*256 bf16

    prep_kernel<<<dim3(256), 256, 0, stream>>>(x, w_qkv, w_out, xb, wb, wob);
    qkv_mfma<<<dim3(32, 24, BB), 256, 0, stream>>>(xb, wb, b_qkv, qb, kb, vtb);
    denom_mfma<<<dim3(512), 512, 0, stream>>>(qb, kb, vtb);
    attn_mfma<<<dim3(512), 512, 0, stream>>>(qb, kb, vtb, attnT);
    out_mfma<<<dim3(256), 256, 0, stream>>>(attnT, wob, x, b_out,
                                            bnw, bnb, bnm, bnv, out);
}

// Round 17
// 70.331 us; speedup vs baseline: 3.8425x; 1.0120x over previous
//
#include <hip/hip_runtime.h>
#include <math.h>

#define BB 4
#define CIN 128
#define LL 2048
#define HH 8
#define CH 32
#define HID 256

typedef __attribute__((ext_vector_type(8))) __bf16 bf16x8;
typedef __attribute__((ext_vector_type(4))) float f32x4;
typedef __attribute__((ext_vector_type(16))) float f32x16;

static __device__ __forceinline__ unsigned int f2bf(float f) {
    union { __bf16 b; unsigned short s; } u;
    u.b = (__bf16)f;
    return (unsigned int)u.s;
}
static __device__ __forceinline__ float bf2f(unsigned int s) {
    union { float f; unsigned int u; } x;
    x.u = s << 16;
    return x.f;
}

#define MFMA   __builtin_amdgcn_mfma_f32_16x16x32_bf16
#define MFMA32 __builtin_amdgcn_mfma_f32_32x32x16_bf16
#define E2(x)  __builtin_amdgcn_exp2f(x)

// ---------------------------------------------------------------------------
// Kernel 1: QKV via bf16 MFMA, fused x-transpose + W conversion (prep gone).
// Block (lt, h, b): stages x-tile fp32->LDS once, loops sel in {q,k,v}.
// Q: [bh][l][d] bf16 pre-scaled by log2(e)/sqrt(L); K: [bh][l][d];
// V: transposed [bh][d][l].
// ---------------------------------------------------------------------------
__global__ __launch_bounds__(256) void qkv_mfma(
        const float* __restrict__ x, const float* __restrict__ w_qkv,
        const float* __restrict__ b_qkv,
        unsigned short* __restrict__ qb, unsigned short* __restrict__ kb,
        unsigned short* __restrict__ vtb) {
    __shared__ float tr2[128][66];             // x^T staging f32: [i][l_local]
    __shared__ unsigned short wlds2[32][136];  // W bf16 [o][i]
    __shared__ float tr[32 * 65];
    const int t = threadIdx.x, w = t >> 6, lane = t & 63;
    const int r = lane & 15, gq = lane >> 4;
    const int lt = blockIdx.x;           // 0..31 (64-l tile)
    const int h  = blockIdx.y;           // 0..7
    const int b  = blockIdx.z;
    const int l0 = lt * 64;

    // stage x tile [128 i][64 l] (coalesced along l)
    {
        const int ll = t & 63, ig = t >> 6;
        const float* xp = x + (size_t)b * CIN * LL + l0 + ll;
        #pragma unroll
        for (int k = 0; k < 32; ++k) {
            const int i = k * 4 + ig;
            tr2[i][ll] = xp[(size_t)i * LL];
        }
    }
    __syncthreads();

    // loop-invariant B-fragments for this wave: lane (r,gq), l = w*16+r
    bf16x8 bfr[4];
    #pragma unroll
    for (int ks = 0; ks < 4; ++ks) {
        union { uint4 u; bf16x8 v; } p;
        const int i0 = gq * 8 + ks * 32, lx = w * 16 + r;
        p.u.x = f2bf(tr2[i0 + 0][lx]) | (f2bf(tr2[i0 + 1][lx]) << 16);
        p.u.y = f2bf(tr2[i0 + 2][lx]) | (f2bf(tr2[i0 + 3][lx]) << 16);
        p.u.z = f2bf(tr2[i0 + 4][lx]) | (f2bf(tr2[i0 + 5][lx]) << 16);
        p.u.w = f2bf(tr2[i0 + 6][lx]) | (f2bf(tr2[i0 + 7][lx]) << 16);
        bfr[ks] = p.v;
    }

    for (int sel = 0; sel < 3; ++sel) {
        const int obase = sel * 256 + h * 32;
        __syncthreads();   // previous sel's epilogue/tr reads & wlds2 reads done
        // stage W rows obase..obase+31 from fp32 (convert inline)
        #pragma unroll
        for (int k2 = 0; k2 < 2; ++k2) {
            int idx = t + k2 * 256;               // 0..511
            int row = idx >> 4, col8 = (idx & 15) * 8;
            const float* wsrc = w_qkv + (size_t)(obase + row) * CIN + col8;
            float4 a4 = *(const float4*)(wsrc);
            float4 b4 = *(const float4*)(wsrc + 4);
            uint4 o;
            o.x = f2bf(a4.x) | (f2bf(a4.y) << 16);
            o.y = f2bf(a4.z) | (f2bf(a4.w) << 16);
            o.z = f2bf(b4.x) | (f2bf(b4.y) << 16);
            o.w = f2bf(b4.z) | (f2bf(b4.w) << 16);
            *(uint4*)&wlds2[row][col8] = o;
        }
        __syncthreads();

        f32x4 acc0 = {0,0,0,0}, acc1 = {0,0,0,0};
        #pragma unroll
        for (int ks = 0; ks < 4; ++ks) {
            bf16x8 a0 = *(const bf16x8*)&wlds2[r][gq * 8 + ks * 32];
            bf16x8 a1 = *(const bf16x8*)&wlds2[16 + r][gq * 8 + ks * 32];
            acc0 = MFMA(a0, bfr[ks], acc0, 0, 0, 0);
            acc1 = MFMA(a1, bfr[ks], acc1, 0, 0, 0);
        }
        const float scale = (sel == 0) ? 0.03187935835f : 1.0f;  // log2(e)/sqrt(2048)
        #pragma unroll
        for (int reg = 0; reg < 4; ++reg) {
            const int oc0 = gq * 4 + reg;
            tr[oc0 * 65 + w * 16 + r] = (acc0[reg] + b_qkv[obase + oc0]) * scale;
            const int oc1 = 16 + gq * 4 + reg;
            tr[oc1 * 65 + w * 16 + r] = (acc1[reg] + b_qkv[obase + oc1]) * scale;
        }
        __syncthreads();

        if (sel == 2) {
            unsigned short* dst = vtb + ((size_t)(b * HH + h) * CH) * LL + l0;
            #pragma unroll
            for (int rr = 0; rr < 8; ++rr) {
                int flat = rr * 256 + t;
                int c = flat >> 6, l = flat & 63;
                dst[(size_t)c * LL + l] = (unsigned short)f2bf(tr[c * 65 + l]);
            }
        } else {
            unsigned short* dst = (sel == 0 ? qb : kb)
                                  + ((size_t)(b * HH + h) * LL + l0) * CH;
            #pragma unroll
            for (int rr = 0; rr < 8; ++rr) {
                int flat = rr * 256 + t;
                int c = flat & 31, lr = flat >> 5;
                dst[flat] = (unsigned short)f2bf(tr[c * 65 + lr]);
            }
        }
    }
}

// ---------------------------------------------------------------------------
// Kernel 2: softmax denominators, LDS-staged K.  R17: 256-a chunks (8 iters,
// 8 barriers).  Then scale V^T in place.
// ---------------------------------------------------------------------------
__global__ __launch_bounds__(512, 4) void denom_mfma(
        const unsigned short* __restrict__ qb,
        const unsigned short* __restrict__ kb,
        unsigned short* __restrict__ vtb) {
    __shared__ unsigned short klds[2][256][40];
    __shared__ float zz[128];
    const int t = threadIdx.x, wave = t >> 6, lane = t & 63;
    const int id = blockIdx.x;                 // 0..511
    const int bh = (id & 7) * 4 + (id >> 7);   // xcd-swizzled
    const int qt = (id >> 3) & 15;             // 128-q tile
    const int r = lane & 15, g = lane >> 4;
    const int q0 = qt * 128 + wave * 16;

    bf16x8 afrag = *(const bf16x8*)(qb + ((size_t)bh * LL + q0 + r) * CH + 8 * g);

    const unsigned short* kbase = kb + (size_t)bh * LL * CH;

    float z0 = 0.f, z1 = 0.f, z2 = 0.f, z3 = 0.f;
    const f32x4 zero = {0.f, 0.f, 0.f, 0.f};

    // prologue: stage chunk 0 (256 a x 32 d = 16KB, 2 uint4 per thread)
    #pragma unroll
    for (int k2 = 0; k2 < 2; ++k2) {
        int ts2 = t + 512 * k2;
        int a = ts2 >> 2, dcol = (ts2 & 3) * 8;
        *(uint4*)(&klds[0][0][0] + a * 40 + dcol) =
            *(const uint4*)(kbase + (size_t)a * CH + dcol);
    }
    __syncthreads();

    const int rb = r * 40 + 8 * g;
    for (int c = 0; c < 8; ++c) {
        const int cur = c & 1;
        uint4 nreg0, nreg1;
        if (c < 7) {
            int ts0 = t, ts1 = t + 512;
            nreg0 = *(const uint4*)(kbase + (size_t)((c + 1) * 256 + (ts0 >> 2)) * CH
                                    + (ts0 & 3) * 8);
            nreg1 = *(const uint4*)(kbase + (size_t)((c + 1) * 256 + (ts1 >> 2)) * CH
                                    + (ts1 & 3) * 8);
        }
        const unsigned short* kc = &klds[cur][0][0];
        #pragma unroll
        for (int s = 0; s < 16; ++s) {
            bf16x8 bf = *(const bf16x8*)(kc + s * 16 * 40 + rb);
            f32x4 d = MFMA(afrag, bf, zero, 0, 0, 0);
            z0 += E2(d[0]); z1 += E2(d[1]); z2 += E2(d[2]); z3 += E2(d[3]);
        }
        if (c < 7) {
            unsigned short* kd = &klds[cur ^ 1][0][0];
            int ts0 = t, ts1 = t + 512;
            *(uint4*)(kd + (ts0 >> 2) * 40 + (ts0 & 3) * 8) = nreg0;
            *(uint4*)(kd + (ts1 >> 2) * 40 + (ts1 & 3) * 8) = nreg1;
        }
        __syncthreads();
    }

    #pragma unroll
    for (int m = 1; m < 16; m <<= 1) {
        z0 += __shfl_xor(z0, m); z1 += __shfl_xor(z1, m);
        z2 += __shfl_xor(z2, m); z3 += __shfl_xor(z3, m);
    }
    if (r == 0)
        *(float4*)&zz[wave * 16 + 4 * g] = make_float4(z0, z1, z2, z3);
    __syncthreads();
    if (t < 128) zz[t] = 1.0f / zz[t];
    __syncthreads();

    const int d = t >> 4, qo = (t & 15) * 8;
    unsigned short* vrow = vtb + ((size_t)bh * CH + d) * LL + qt * 128 + qo;
    uint4 v = *(const uint4*)vrow;
    const float* zp = &zz[qo];
    unsigned int w0, w1, w2, w3;
    w0 = f2bf(bf2f(v.x & 0xFFFFu) * zp[0]) | (f2bf(bf2f(v.x >> 16) * zp[1]) << 16);
    w1 = f2bf(bf2f(v.y & 0xFFFFu) * zp[2]) | (f2bf(bf2f(v.y >> 16) * zp[3]) << 16);
    w2 = f2bf(bf2f(v.z & 0xFFFFu) * zp[4]) | (f2bf(bf2f(v.z >> 16) * zp[5]) << 16);
    w3 = f2bf(bf2f(v.w & 0xFFFFu) * zp[6]) | (f2bf(bf2f(v.w >> 16) * zp[7]) << 16);
    *(uint4*)vrow = make_uint4(w0, w1, w2, w3);
}

// ---------------------------------------------------------------------------
// Kernel 3: attn^T via 32x32x16 MFMA + in-register softmax transpose.
// R17: 128-q chunks (8 iters, 8 barriers); waves 0-3 stage Q (8KB),
// waves 4-7 stage V (8KB); 2 uint4 per stager per chunk.
// ---------------------------------------------------------------------------
__global__ __launch_bounds__(512, 4) void attn_mfma(
        const unsigned short* __restrict__ qb,
        const unsigned short* __restrict__ kb,
        const unsigned short* __restrict__ vtb,
        float* __restrict__ attnT) {
    __shared__ unsigned short qlds[2][128][40];   // [q][d]
    __shared__ unsigned short vlds[2][128][40];   // [sub*32+d][q]
    const int t = threadIdx.x, wave = t >> 6, lane = t & 63;
    const int ln = lane & 31, hi = lane >> 5;
    const int id = blockIdx.x;                    // 0..511
    const int bhqh = (id & 7) * 8 + (id >> 6);    // xcd-swizzled (bh,qh)
    const int at = (id >> 3) & 7;
    const int bh = bhqh >> 1, qh = bhqh & 1;
    const int b = bh >> 3, h = bh & 7;
    const int a0 = at * 256 + wave * 32;
    const int q00 = qh * 1024;

    const unsigned short* kp = kb + ((size_t)bh * LL + a0 + ln) * CH + 8 * hi;
    const bf16x8 kf0 = *(const bf16x8*)kp;
    const bf16x8 kf1 = *(const bf16x8*)(kp + 16);

    unsigned short* const ql0 = &qlds[0][0][0];
    unsigned short* const ql1 = &qlds[1][0][0];
    unsigned short* const vl0 = &vlds[0][0][0];
    unsigned short* const vl1 = &vlds[1][0][0];

    // staging addresses (2 slots per stager thread)
    const int ts = t & 255;
    int sq[2], sv[2];
    const unsigned short *qsa[2], *vsa[2];
    #pragma unroll
    for (int k2 = 0; k2 < 2; ++k2) {
        int ts2 = ts + 256 * k2;                  // 0..511
        int q = ts2 >> 2, dcol = (ts2 & 3) * 8;
        qsa[k2] = qb + ((size_t)bh * LL + q00 + q) * CH + dcol;
        sq[k2] = q * 40 + dcol;
        int sub = ts2 >> 7, vd = (ts2 >> 2) & 31, vq = (ts2 & 3) * 8;
        vsa[k2] = vtb + ((size_t)bh * CH + vd) * LL + q00 + sub * 32 + vq;
        sv[k2] = (sub * 32 + vd) * 40 + vq;
    }

    f32x16 acc = {0.f,0.f,0.f,0.f,0.f,0.f,0.f,0.f,0.f,0.f,0.f,0.f,0.f,0.f,0.f,0.f};
    const f32x16 zero16 = {0.f,0.f,0.f,0.f,0.f,0.f,0.f,0.f,0.f,0.f,0.f,0.f,0.f,0.f,0.f,0.f};

#define CVTPK(dst, lo_, hi_) \
    asm("v_cvt_pk_bf16_f32 %0, %1, %2" : "=v"(dst) : "v"(lo_), "v"(hi_))
#define SWAPH(a_, b_) \
    asm("v_permlane32_swap_b32 %0, %1" : "+v"(a_), "+v"(b_))

    // prologue: stage chunk 0 into buf 0
    #pragma unroll
    for (int k2 = 0; k2 < 2; ++k2) {
        if (wave < 4) *(uint4*)(ql0 + sq[k2]) = *(const uint4*)(qsa[k2]);
        else          *(uint4*)(vl0 + sv[k2]) = *(const uint4*)(vsa[k2]);
    }
    __syncthreads();

    for (int n = 0; n < 8; ++n) {
        const int cur = n & 1;
        uint4 nreg0, nreg1;
        if (n < 7) {
            if (wave < 4) {
                nreg0 = *(const uint4*)(qsa[0] + (size_t)(n + 1) * 128 * CH);
                nreg1 = *(const uint4*)(qsa[1] + (size_t)(n + 1) * 128 * CH);
            } else {
                nreg0 = *(const uint4*)(vsa[0] + (n + 1) * 128);
                nreg1 = *(const uint4*)(vsa[1] + (n + 1) * 128);
            }
        }
        const unsigned short* qc = cur ? ql1 : ql0;
        const unsigned short* vc = cur ? vl1 : vl0;
        #pragma unroll
        for (int s2 = 0; s2 < 4; ++s2) {
            const int rdq = (s2 * 32 + ln) * 40 + 8 * hi;
            bf16x8 qa0 = *(const bf16x8*)(qc + rdq);
            bf16x8 qa1 = *(const bf16x8*)(qc + rdq + 16);
            bf16x8 vb0 = *(const bf16x8*)(vc + rdq);
            bf16x8 vb1 = *(const bf16x8*)(vc + rdq + 16);
            f32x16 s = MFMA32(qa0, kf0, zero16, 0, 0, 0);
            s = MFMA32(qa1, kf1, s, 0, 0, 0);
            unsigned int w0, w1, w2, w3, w4, w5, w6, w7;
            {
                float p0  = E2(s[0]),  p1  = E2(s[1]),  p2  = E2(s[2]),  p3  = E2(s[3]);
                float p4  = E2(s[4]),  p5  = E2(s[5]),  p6  = E2(s[6]),  p7  = E2(s[7]);
                float p8  = E2(s[8]),  p9  = E2(s[9]),  p10 = E2(s[10]), p11 = E2(s[11]);
                float p12 = E2(s[12]), p13 = E2(s[13]), p14 = E2(s[14]), p15 = E2(s[15]);
                CVTPK(w0, p0,  p1);  CVTPK(w1, p2,  p3);
                CVTPK(w2, p4,  p5);  CVTPK(w3, p6,  p7);
                CVTPK(w4, p8,  p9);  CVTPK(w5, p10, p11);
                CVTPK(w6, p12, p13); CVTPK(w7, p14, p15);
                SWAPH(w0, w2); SWAPH(w1, w3); SWAPH(w4, w6); SWAPH(w5, w7);
            }
            union { uint4 u; bf16x8 v; } pa0, pa1;
            pa0.u = make_uint4(w0, w1, w2, w3);
            pa1.u = make_uint4(w4, w5, w6, w7);
            __builtin_amdgcn_s_setprio(1);
            acc = MFMA32(pa0.v, vb0, acc, 0, 0, 0);
            acc = MFMA32(pa1.v, vb1, acc, 0, 0, 0);
            __builtin_amdgcn_s_setprio(0);
        }
        if (n < 7) {
            unsigned short* qd = cur ? ql0 : ql1;
            unsigned short* vd = cur ? vl0 : vl1;
            if (wave < 4) {
                *(uint4*)(qd + sq[0]) = nreg0;
                *(uint4*)(qd + sq[1]) = nreg1;
            } else {
                *(uint4*)(vd + sv[0]) = nreg0;
                *(uint4*)(vd + sv[1]) = nreg1;
            }
        }
        __syncthreads();
    }

#undef SWAPH
#undef CVTPK

    float* ob = attnT + ((size_t)qh * BB * HID + (size_t)b * HID + h * CH + ln) * LL
                + a0 + 4 * hi;
    *(f32x4*)(ob +  0) = __builtin_shufflevector(acc, acc,  0,  1,  2,  3);
    *(f32x4*)(ob +  8) = __builtin_shufflevector(acc, acc,  4,  5,  6,  7);
    *(f32x4*)(ob + 16) = __builtin_shufflevector(acc, acc,  8,  9, 10, 11);
    *(f32x4*)(ob + 24) = __builtin_shufflevector(acc, acc, 12, 13, 14, 15);
}

// ---------------------------------------------------------------------------
// Kernel 4: out projection via MFMA GEMM; W staged from fp32 (convert inline).
// ---------------------------------------------------------------------------
__global__ __launch_bounds__(256, 4) void out_mfma(
        const float* __restrict__ attnT, const float* __restrict__ w_out,
        const float* __restrict__ x, const float* __restrict__ b_out,
        const float* __restrict__ bnw, const float* __restrict__ bnb,
        const float* __restrict__ bnm, const float* __restrict__ bnv,
        float* __restrict__ out) {
    __shared__ unsigned short alds[2][32][40];    // [l][i] bf16
    __shared__ unsigned short wlds[2][128][40];   // [o][i] bf16
    const int t = threadIdx.x, wave = t >> 6, lane = t & 63;
    const int ln = lane & 31, hi = lane >> 5;
    const int id = blockIdx.x;                    // 0..255
    const int bid = (id & 7) * 32 + (id >> 3);    // xcd swizzle
    const int b = bid >> 6, lt = bid & 63;
    const int l0 = lt * 32;
    const size_t PART = (size_t)BB * HID * LL;
    const int WBUF = 128 * 40;

    const int si = t >> 3, sl4 = (t & 7) * 4;
    const float* ap0 = attnT + ((size_t)b * HID + si) * LL + l0 + sl4;
    const float* wsrc0 = w_out + (size_t)(t >> 2) * HID + (t & 3) * 8;
    const float* wsrc1 = wsrc0 + (size_t)64 * HID;
    unsigned short* const wdst0 = &wlds[0][t >> 2][(t & 3) * 8];

    f32x16 acc = {0.f,0.f,0.f,0.f,0.f,0.f,0.f,0.f,0.f,0.f,0.f,0.f,0.f,0.f,0.f,0.f};

#define PACKW(dst, p) do { \
    float4 a4 = *(const float4*)(p); \
    float4 b4 = *(const float4*)((p) + 4); \
    uint4 o_; \
    o_.x = f2bf(a4.x) | (f2bf(a4.y) << 16); \
    o_.y = f2bf(a4.z) | (f2bf(a4.w) << 16); \
    o_.z = f2bf(b4.x) | (f2bf(b4.y) << 16); \
    o_.w = f2bf(b4.z) | (f2bf(b4.w) << 16); \
    *(uint4*)(dst) = o_; \
} while (0)

    {
        f32x4 a0 = *(const f32x4*)(ap0);
        f32x4 a1 = *(const f32x4*)(ap0 + PART);
        #pragma unroll
        for (int j = 0; j < 4; ++j)
            alds[0][sl4 + j][si] = (unsigned short)f2bf(a0[j] + a1[j]);
        PACKW(wdst0, wsrc0);
        PACKW(wdst0 + 64 * 40, wsrc1);
    }
    __syncthreads();

    for (int c = 0; c < 8; ++c) {
        const int cur = c & 1;
        f32x4 na0, na1;
        if (c < 7) {
            na0 = *(const f32x4*)(ap0 + (size_t)(c + 1) * 32 * LL);
            na1 = *(const f32x4*)(ap0 + (size_t)(c + 1) * 32 * LL + PART);
        }
        const unsigned short* wc = &wlds[cur][0][0] + (wave * 32 + ln) * 40 + 8 * hi;
        const unsigned short* ac = &alds[cur][0][0] + ln * 40 + 8 * hi;
        bf16x8 af0 = *(const bf16x8*)(wc);
        bf16x8 af1 = *(const bf16x8*)(wc + 16);
        bf16x8 bf0 = *(const bf16x8*)(ac);
        bf16x8 bf1 = *(const bf16x8*)(ac + 16);
        acc = MFMA32(af0, bf0, acc, 0, 0, 0);
        acc = MFMA32(af1, bf1, acc, 0, 0, 0);
        if (c < 7) {
            const int nb = cur ^ 1;
            #pragma unroll
            for (int j = 0; j < 4; ++j)
                alds[nb][sl4 + j][si] = (unsigned short)f2bf(na0[j] + na1[j]);
            PACKW(wdst0 + nb * WBUF, wsrc0 + (c + 1) * 32);
            PACKW(wdst0 + nb * WBUF + 64 * 40, wsrc1 + (c + 1) * 32);
        }
        __syncthreads();
    }
#undef PACKW

    #pragma unroll
    for (int reg = 0; reg < 16; ++reg) {
        const int o = wave * 32 + (reg & 3) + 8 * (reg >> 2) + 4 * hi;
        const float inv = bnw[o] / sqrtf(bnv[o] + 1e-5f);
        const float sh  = bnb[o] - bnm[o] * inv;
        const size_t idx = ((size_t)b * CIN + o) * LL + l0 + ln;
        float val = acc[reg] + b_out[o] + x[idx];
        out[idx] = val * inv + sh;
    }
}

// ---------------------------------------------------------------------------
extern "C" void kernel_launch(void* const* d_in, const int* in_sizes, int n_in,
                              void* d_out, int out_size, void* d_ws, size_t ws_size,
                              hipStream_t stream) {
    const float* x      = (const float*)d_in[0];
    const float* w_qkv  = (const float*)d_in[1];
    const float* b_qkv  = (const float*)d_in[2];
    const float* w_out  = (const float*)d_in[3];
    const float* b_out  = (const float*)d_in[4];
    const float* bnw    = (const float*)d_in[5];
    const float* bnb    = (const float*)d_in[6];
    const float* bnm    = (const float*)d_in[7];
    const float* bnv    = (const float*)d_in[8];
    float* out = (float*)d_out;

    const size_t NBH = (size_t)BB * HH;          // 32
    const size_t QKV_ELEMS = NBH * LL * CH;      // 2,097,152 bf16 elems each
    unsigned short* qb    = (unsigned short*)d_ws;
    unsigned short* kb    = qb + QKV_ELEMS;
    unsigned short* vtb   = kb + QKV_ELEMS;
    float* attnT = (float*)(vtb + QKV_ELEMS);    // 2 x 8 MB f32 partials

    qkv_mfma<<<dim3(32, 8, BB), 256, 0, stream>>>(x, w_qkv, b_qkv, qb, kb, vtb);
    denom_mfma<<<dim3(512), 512, 0, stream>>>(qb, kb, vtb);
    attn_mfma<<<dim3(512), 512, 0, stream>>>(qb, kb, vtb, attnT);
    out_mfma<<<dim3(256), 256, 0, stream>>>(attnT, w_out, x, b_out,
                                            bnw, bnb, bnm, bnv, out);
}

// Round 19
// 69.277 us; speedup vs baseline: 3.9010x; 1.0152x over previous
//
#include <hip/hip_runtime.h>
#include <math.h>

#define BB 4
#define CIN 128
#define LL 2048
#define HH 8
#define CH 32
#define HID 256

typedef __attribute__((ext_vector_type(8))) __bf16 bf16x8;
typedef __attribute__((ext_vector_type(4))) float f32x4;
typedef __attribute__((ext_vector_type(16))) float f32x16;

static __device__ __forceinline__ unsigned int f2bf(float f) {
    union { __bf16 b; unsigned short s; } u;
    u.b = (__bf16)f;
    return (unsigned int)u.s;
}
static __device__ __forceinline__ float bf2f(unsigned int s) {
    union { float f; unsigned int u; } x;
    x.u = s << 16;
    return x.f;
}

#define MFMA   __builtin_amdgcn_mfma_f32_16x16x32_bf16
#define MFMA32 __builtin_amdgcn_mfma_f32_32x32x16_bf16
#define E2(x)  __builtin_amdgcn_exp2f(x)

// ---------------------------------------------------------------------------
// Kernel 1: QKV via bf16 MFMA, fused x-transpose + W conversion (R17-proven).
// ---------------------------------------------------------------------------
__global__ __launch_bounds__(256) void qkv_mfma(
        const float* __restrict__ x, const float* __restrict__ w_qkv,
        const float* __restrict__ b_qkv,
        unsigned short* __restrict__ qb, unsigned short* __restrict__ kb,
        unsigned short* __restrict__ vtb) {
    __shared__ float tr2[128][66];             // x^T staging f32: [i][l_local]
    __shared__ unsigned short wlds2[32][136];  // W bf16 [o][i]
    __shared__ float tr[32 * 65];
    const int t = threadIdx.x, w = t >> 6, lane = t & 63;
    const int r = lane & 15, gq = lane >> 4;
    const int lt = blockIdx.x;           // 0..31 (64-l tile)
    const int h  = blockIdx.y;           // 0..7
    const int b  = blockIdx.z;
    const int l0 = lt * 64;

    {
        const int ll = t & 63, ig = t >> 6;
        const float* xp = x + (size_t)b * CIN * LL + l0 + ll;
        #pragma unroll
        for (int k = 0; k < 32; ++k) {
            const int i = k * 4 + ig;
            tr2[i][ll] = xp[(size_t)i * LL];
        }
    }
    __syncthreads();

    bf16x8 bfr[4];
    #pragma unroll
    for (int ks = 0; ks < 4; ++ks) {
        union { uint4 u; bf16x8 v; } p;
        const int i0 = gq * 8 + ks * 32, lx = w * 16 + r;
        p.u.x = f2bf(tr2[i0 + 0][lx]) | (f2bf(tr2[i0 + 1][lx]) << 16);
        p.u.y = f2bf(tr2[i0 + 2][lx]) | (f2bf(tr2[i0 + 3][lx]) << 16);
        p.u.z = f2bf(tr2[i0 + 4][lx]) | (f2bf(tr2[i0 + 5][lx]) << 16);
        p.u.w = f2bf(tr2[i0 + 6][lx]) | (f2bf(tr2[i0 + 7][lx]) << 16);
        bfr[ks] = p.v;
    }

    for (int sel = 0; sel < 3; ++sel) {
        const int obase = sel * 256 + h * 32;
        __syncthreads();
        #pragma unroll
        for (int k2 = 0; k2 < 2; ++k2) {
            int idx = t + k2 * 256;
            int row = idx >> 4, col8 = (idx & 15) * 8;
            const float* wsrc = w_qkv + (size_t)(obase + row) * CIN + col8;
            float4 a4 = *(const float4*)(wsrc);
            float4 b4 = *(const float4*)(wsrc + 4);
            uint4 o;
            o.x = f2bf(a4.x) | (f2bf(a4.y) << 16);
            o.y = f2bf(a4.z) | (f2bf(a4.w) << 16);
            o.z = f2bf(b4.x) | (f2bf(b4.y) << 16);
            o.w = f2bf(b4.z) | (f2bf(b4.w) << 16);
            *(uint4*)&wlds2[row][col8] = o;
        }
        __syncthreads();

        f32x4 acc0 = {0,0,0,0}, acc1 = {0,0,0,0};
        #pragma unroll
        for (int ks = 0; ks < 4; ++ks) {
            bf16x8 a0 = *(const bf16x8*)&wlds2[r][gq * 8 + ks * 32];
            bf16x8 a1 = *(const bf16x8*)&wlds2[16 + r][gq * 8 + ks * 32];
            acc0 = MFMA(a0, bfr[ks], acc0, 0, 0, 0);
            acc1 = MFMA(a1, bfr[ks], acc1, 0, 0, 0);
        }
        const float scale = (sel == 0) ? 0.03187935835f : 1.0f;  // log2(e)/sqrt(2048)
        #pragma unroll
        for (int reg = 0; reg < 4; ++reg) {
            const int oc0 = gq * 4 + reg;
            tr[oc0 * 65 + w * 16 + r] = (acc0[reg] + b_qkv[obase + oc0]) * scale;
            const int oc1 = 16 + gq * 4 + reg;
            tr[oc1 * 65 + w * 16 + r] = (acc1[reg] + b_qkv[obase + oc1]) * scale;
        }
        __syncthreads();

        if (sel == 2) {
            unsigned short* dst = vtb + ((size_t)(b * HH + h) * CH) * LL + l0;
            #pragma unroll
            for (int rr = 0; rr < 8; ++rr) {
                int flat = rr * 256 + t;
                int c = flat >> 6, l = flat & 63;
                dst[(size_t)c * LL + l] = (unsigned short)f2bf(tr[c * 65 + l]);
            }
        } else {
            unsigned short* dst = (sel == 0 ? qb : kb)
                                  + ((size_t)(b * HH + h) * LL + l0) * CH;
            #pragma unroll
            for (int rr = 0; rr < 8; ++rr) {
                int flat = rr * 256 + t;
                int c = flat & 31, lr = flat >> 5;
                dst[flat] = (unsigned short)f2bf(tr[c * 65 + lr]);
            }
        }
    }
}

// ---------------------------------------------------------------------------
// Kernel 2: softmax denominators, LDS-staged K (R17-proven).
// ---------------------------------------------------------------------------
__global__ __launch_bounds__(512, 4) void denom_mfma(
        const unsigned short* __restrict__ qb,
        const unsigned short* __restrict__ kb,
        unsigned short* __restrict__ vtb) {
    __shared__ unsigned short klds[2][256][40];
    __shared__ float zz[128];
    const int t = threadIdx.x, wave = t >> 6, lane = t & 63;
    const int id = blockIdx.x;                 // 0..511
    const int bh = (id & 7) * 4 + (id >> 7);   // xcd-swizzled
    const int qt = (id >> 3) & 15;             // 128-q tile
    const int r = lane & 15, g = lane >> 4;
    const int q0 = qt * 128 + wave * 16;

    bf16x8 afrag = *(const bf16x8*)(qb + ((size_t)bh * LL + q0 + r) * CH + 8 * g);

    const unsigned short* kbase = kb + (size_t)bh * LL * CH;

    float z0 = 0.f, z1 = 0.f, z2 = 0.f, z3 = 0.f;
    const f32x4 zero = {0.f, 0.f, 0.f, 0.f};

    #pragma unroll
    for (int k2 = 0; k2 < 2; ++k2) {
        int ts2 = t + 512 * k2;
        int a = ts2 >> 2, dcol = (ts2 & 3) * 8;
        *(uint4*)(&klds[0][0][0] + a * 40 + dcol) =
            *(const uint4*)(kbase + (size_t)a * CH + dcol);
    }
    __syncthreads();

    const int rb = r * 40 + 8 * g;
    for (int c = 0; c < 8; ++c) {
        const int cur = c & 1;
        uint4 nreg0, nreg1;
        if (c < 7) {
            int ts0 = t, ts1 = t + 512;
            nreg0 = *(const uint4*)(kbase + (size_t)((c + 1) * 256 + (ts0 >> 2)) * CH
                                    + (ts0 & 3) * 8);
            nreg1 = *(const uint4*)(kbase + (size_t)((c + 1) * 256 + (ts1 >> 2)) * CH
                                    + (ts1 & 3) * 8);
        }
        const unsigned short* kc = &klds[cur][0][0];
        #pragma unroll
        for (int s = 0; s < 16; ++s) {
            bf16x8 bf = *(const bf16x8*)(kc + s * 16 * 40 + rb);
            f32x4 d = MFMA(afrag, bf, zero, 0, 0, 0);
            z0 += E2(d[0]); z1 += E2(d[1]); z2 += E2(d[2]); z3 += E2(d[3]);
        }
        if (c < 7) {
            unsigned short* kd = &klds[cur ^ 1][0][0];
            int ts0 = t, ts1 = t + 512;
            *(uint4*)(kd + (ts0 >> 2) * 40 + (ts0 & 3) * 8) = nreg0;
            *(uint4*)(kd + (ts1 >> 2) * 40 + (ts1 & 3) * 8) = nreg1;
        }
        __syncthreads();
    }

    #pragma unroll
    for (int m = 1; m < 16; m <<= 1) {
        z0 += __shfl_xor(z0, m); z1 += __shfl_xor(z1, m);
        z2 += __shfl_xor(z2, m); z3 += __shfl_xor(z3, m);
    }
    if (r == 0)
        *(float4*)&zz[wave * 16 + 4 * g] = make_float4(z0, z1, z2, z3);
    __syncthreads();
    if (t < 128) zz[t] = 1.0f / zz[t];
    __syncthreads();

    const int d = t >> 4, qo = (t & 15) * 8;
    unsigned short* vrow = vtb + ((size_t)bh * CH + d) * LL + qt * 128 + qo;
    uint4 v = *(const uint4*)vrow;
    const float* zp = &zz[qo];
    unsigned int w0, w1, w2, w3;
    w0 = f2bf(bf2f(v.x & 0xFFFFu) * zp[0]) | (f2bf(bf2f(v.x >> 16) * zp[1]) << 16);
    w1 = f2bf(bf2f(v.y & 0xFFFFu) * zp[2]) | (f2bf(bf2f(v.y >> 16) * zp[3]) << 16);
    w2 = f2bf(bf2f(v.z & 0xFFFFu) * zp[4]) | (f2bf(bf2f(v.z >> 16) * zp[5]) << 16);
    w3 = f2bf(bf2f(v.w & 0xFFFFu) * zp[6]) | (f2bf(bf2f(v.w >> 16) * zp[7]) << 16);
    *(uint4*)vrow = make_uint4(w0, w1, w2, w3);
}

// ---------------------------------------------------------------------------
// Kernel 3: attn^T via 32x32x16 MFMA + in-register softmax transpose
// (R17-proven).
// ---------------------------------------------------------------------------
__global__ __launch_bounds__(512, 4) void attn_mfma(
        const unsigned short* __restrict__ qb,
        const unsigned short* __restrict__ kb,
        const unsigned short* __restrict__ vtb,
        float* __restrict__ attnT) {
    __shared__ unsigned short qlds[2][128][40];   // [q][d]
    __shared__ unsigned short vlds[2][128][40];   // [sub*32+d][q]
    const int t = threadIdx.x, wave = t >> 6, lane = t & 63;
    const int ln = lane & 31, hi = lane >> 5;
    const int id = blockIdx.x;                    // 0..511
    const int bhqh = (id & 7) * 8 + (id >> 6);    // xcd-swizzled (bh,qh)
    const int at = (id >> 3) & 7;
    const int bh = bhqh >> 1, qh = bhqh & 1;
    const int b = bh >> 3, h = bh & 7;
    const int a0 = at * 256 + wave * 32;
    const int q00 = qh * 1024;

    const unsigned short* kp = kb + ((size_t)bh * LL + a0 + ln) * CH + 8 * hi;
    const bf16x8 kf0 = *(const bf16x8*)kp;
    const bf16x8 kf1 = *(const bf16x8*)(kp + 16);

    unsigned short* const ql0 = &qlds[0][0][0];
    unsigned short* const ql1 = &qlds[1][0][0];
    unsigned short* const vl0 = &vlds[0][0][0];
    unsigned short* const vl1 = &vlds[1][0][0];

    const int ts = t & 255;
    int sq[2], sv[2];
    const unsigned short *qsa[2], *vsa[2];
    #pragma unroll
    for (int k2 = 0; k2 < 2; ++k2) {
        int ts2 = ts + 256 * k2;                  // 0..511
        int q = ts2 >> 2, dcol = (ts2 & 3) * 8;
        qsa[k2] = qb + ((size_t)bh * LL + q00 + q) * CH + dcol;
        sq[k2] = q * 40 + dcol;
        int sub = ts2 >> 7, vd = (ts2 >> 2) & 31, vq = (ts2 & 3) * 8;
        vsa[k2] = vtb + ((size_t)bh * CH + vd) * LL + q00 + sub * 32 + vq;
        sv[k2] = (sub * 32 + vd) * 40 + vq;
    }

    f32x16 acc = {0.f,0.f,0.f,0.f,0.f,0.f,0.f,0.f,0.f,0.f,0.f,0.f,0.f,0.f,0.f,0.f};
    const f32x16 zero16 = {0.f,0.f,0.f,0.f,0.f,0.f,0.f,0.f,0.f,0.f,0.f,0.f,0.f,0.f,0.f,0.f};

#define CVTPK(dst, lo_, hi_) \
    asm("v_cvt_pk_bf16_f32 %0, %1, %2" : "=v"(dst) : "v"(lo_), "v"(hi_))
#define SWAPH(a_, b_) \
    asm("v_permlane32_swap_b32 %0, %1" : "+v"(a_), "+v"(b_))

    #pragma unroll
    for (int k2 = 0; k2 < 2; ++k2) {
        if (wave < 4) *(uint4*)(ql0 + sq[k2]) = *(const uint4*)(qsa[k2]);
        else          *(uint4*)(vl0 + sv[k2]) = *(const uint4*)(vsa[k2]);
    }
    __syncthreads();

    for (int n = 0; n < 8; ++n) {
        const int cur = n & 1;
        uint4 nreg0, nreg1;
        if (n < 7) {
            if (wave < 4) {
                nreg0 = *(const uint4*)(qsa[0] + (size_t)(n + 1) * 128 * CH);
                nreg1 = *(const uint4*)(qsa[1] + (size_t)(n + 1) * 128 * CH);
            } else {
                nreg0 = *(const uint4*)(vsa[0] + (n + 1) * 128);
                nreg1 = *(const uint4*)(vsa[1] + (n + 1) * 128);
            }
        }
        const unsigned short* qc = cur ? ql1 : ql0;
        const unsigned short* vc = cur ? vl1 : vl0;
        #pragma unroll
        for (int s2 = 0; s2 < 4; ++s2) {
            const int rdq = (s2 * 32 + ln) * 40 + 8 * hi;
            bf16x8 qa0 = *(const bf16x8*)(qc + rdq);
            bf16x8 qa1 = *(const bf16x8*)(qc + rdq + 16);
            bf16x8 vb0 = *(const bf16x8*)(vc + rdq);
            bf16x8 vb1 = *(const bf16x8*)(vc + rdq + 16);
            f32x16 s = MFMA32(qa0, kf0, zero16, 0, 0, 0);
            s = MFMA32(qa1, kf1, s, 0, 0, 0);
            unsigned int w0, w1, w2, w3, w4, w5, w6, w7;
            {
                float p0  = E2(s[0]),  p1  = E2(s[1]),  p2  = E2(s[2]),  p3  = E2(s[3]);
                float p4  = E2(s[4]),  p5  = E2(s[5]),  p6  = E2(s[6]),  p7  = E2(s[7]);
                float p8  = E2(s[8]),  p9  = E2(s[9]),  p10 = E2(s[10]), p11 = E2(s[11]);
                float p12 = E2(s[12]), p13 = E2(s[13]), p14 = E2(s[14]), p15 = E2(s[15]);
                CVTPK(w0, p0,  p1);  CVTPK(w1, p2,  p3);
                CVTPK(w2, p4,  p5);  CVTPK(w3, p6,  p7);
                CVTPK(w4, p8,  p9);  CVTPK(w5, p10, p11);
                CVTPK(w6, p12, p13); CVTPK(w7, p14, p15);
                SWAPH(w0, w2); SWAPH(w1, w3); SWAPH(w4, w6); SWAPH(w5, w7);
            }
            union { uint4 u; bf16x8 v; } pa0, pa1;
            pa0.u = make_uint4(w0, w1, w2, w3);
            pa1.u = make_uint4(w4, w5, w6, w7);
            __builtin_amdgcn_s_setprio(1);
            acc = MFMA32(pa0.v, vb0, acc, 0, 0, 0);
            acc = MFMA32(pa1.v, vb1, acc, 0, 0, 0);
            __builtin_amdgcn_s_setprio(0);
        }
        if (n < 7) {
            unsigned short* qd = cur ? ql0 : ql1;
            unsigned short* vd = cur ? vl0 : vl1;
            if (wave < 4) {
                *(uint4*)(qd + sq[0]) = nreg0;
                *(uint4*)(qd + sq[1]) = nreg1;
            } else {
                *(uint4*)(vd + sv[0]) = nreg0;
                *(uint4*)(vd + sv[1]) = nreg1;
            }
        }
        __syncthreads();
    }

#undef SWAPH
#undef CVTPK

    float* ob = attnT + ((size_t)qh * BB * HID + (size_t)b * HID + h * CH + ln) * LL
                + a0 + 4 * hi;
    *(f32x4*)(ob +  0) = __builtin_shufflevector(acc, acc,  0,  1,  2,  3);
    *(f32x4*)(ob +  8) = __builtin_shufflevector(acc, acc,  4,  5,  6,  7);
    *(f32x4*)(ob + 16) = __builtin_shufflevector(acc, acc,  8,  9, 10, 11);
    *(f32x4*)(ob + 24) = __builtin_shufflevector(acc, acc, 12, 13, 14, 15);
}

// ---------------------------------------------------------------------------
// Kernel 4: out projection via MFMA GEMM.  R18: 512 blocks (2x occupancy).
// Block = (b, 32-l tile, o-half of 64).  4 waves = 2 o-tiles x 2 K-halves;
// chunk c stages two 32-i slices (one per K-half); LDS pair-reduce at end.
// ---------------------------------------------------------------------------
__global__ __launch_bounds__(256, 4) void out_mfma(
        const float* __restrict__ attnT, const float* __restrict__ w_out,
        const float* __restrict__ x, const float* __restrict__ b_out,
        const float* __restrict__ bnw, const float* __restrict__ bnb,
        const float* __restrict__ bnm, const float* __restrict__ bnv,
        float* __restrict__ out) {
    __shared__ unsigned short alds[2][2][32][40];  // [buf][slice][l][i] bf16
    __shared__ unsigned short wlds[2][2][64][40];  // [buf][slice][o][i] bf16
    __shared__ float red[2][32][33];               // [otile][o_local][l]
    const int t = threadIdx.x, wave = t >> 6, lane = t & 63;
    const int ln = lane & 31, hi = lane >> 5;
    const int otile = wave >> 1, khalf = wave & 1;
    const int id = blockIdx.x;                    // 0..511
    const int bid = (id & 7) * 64 + (id >> 3);    // xcd swizzle
    const int b = bid >> 7;
    const int rest = bid & 127;
    const int lt = rest >> 1, oh = rest & 1;
    const int l0 = lt * 32;
    const int obase = oh * 64;
    const size_t PART = (size_t)BB * HID * LL;

    // --- staging maps ---
    // A: slice s = t>>7; i = (t&127)>>2 (32 i/slice); l8 = (t&3)*8 (8 l)
    const int as = t >> 7, ai = (t & 127) >> 2, al8 = (t & 3) * 8;
    const float* apb = attnT + ((size_t)b * HID + as * 128 + ai) * LL + l0 + al8;
    // W: slice s = t>>7; row = (t&127)>>1 (64 o/slice); colg = (t&1)*16
    const int ws = t >> 7, wrow = (t & 127) >> 1, wcolg = (t & 1) * 16;
    const float* wpb = w_out + (size_t)(obase + wrow) * HID + ws * 128 + wcolg;

    f32x16 acc = {0.f,0.f,0.f,0.f,0.f,0.f,0.f,0.f,0.f,0.f,0.f,0.f,0.f,0.f,0.f,0.f};

    // prologue: stage chunk 0
    {
        f32x4 a0 = *(const f32x4*)(apb);
        f32x4 a0b = *(const f32x4*)(apb + 4);
        f32x4 a1 = *(const f32x4*)(apb + PART);
        f32x4 a1b = *(const f32x4*)(apb + PART + 4);
        #pragma unroll
        for (int j = 0; j < 4; ++j) {
            alds[0][as][al8 + j][ai]     = (unsigned short)f2bf(a0[j] + a1[j]);
            alds[0][as][al8 + 4 + j][ai] = (unsigned short)f2bf(a0b[j] + a1b[j]);
        }
        float4 wa = *(const float4*)(wpb);
        float4 wb2 = *(const float4*)(wpb + 4);
        float4 wc = *(const float4*)(wpb + 8);
        float4 wd = *(const float4*)(wpb + 12);
        uint4 o_;
        o_.x = f2bf(wa.x) | (f2bf(wa.y) << 16);
        o_.y = f2bf(wa.z) | (f2bf(wa.w) << 16);
        o_.z = f2bf(wb2.x) | (f2bf(wb2.y) << 16);
        o_.w = f2bf(wb2.z) | (f2bf(wb2.w) << 16);
        *(uint4*)&wlds[0][ws][wrow][wcolg] = o_;
        o_.x = f2bf(wc.x) | (f2bf(wc.y) << 16);
        o_.y = f2bf(wc.z) | (f2bf(wc.w) << 16);
        o_.z = f2bf(wd.x) | (f2bf(wd.y) << 16);
        o_.w = f2bf(wd.z) | (f2bf(wd.w) << 16);
        *(uint4*)&wlds[0][ws][wrow][wcolg + 8] = o_;
    }
    __syncthreads();

    for (int c = 0; c < 4; ++c) {
        const int cur = c & 1;
        f32x4 na0, na0b, na1, na1b;
        float4 nwa, nwb, nwc, nwd;
        if (c < 3) {
            const float* apn = apb + (size_t)(c + 1) * 32 * LL;
            na0  = *(const f32x4*)(apn);
            na0b = *(const f32x4*)(apn + 4);
            na1  = *(const f32x4*)(apn + PART);
            na1b = *(const f32x4*)(apn + PART + 4);
            const float* wpn = wpb + (c + 1) * 32;
            nwa = *(const float4*)(wpn);
            nwb = *(const float4*)(wpn + 4);
            nwc = *(const float4*)(wpn + 8);
            nwd = *(const float4*)(wpn + 12);
        }
        // fragments: wave (otile, khalf)
        const unsigned short* wc_ = &wlds[cur][khalf][otile * 32 + ln][8 * hi];
        const unsigned short* ac_ = &alds[cur][khalf][ln][8 * hi];
        bf16x8 af0 = *(const bf16x8*)(wc_);
        bf16x8 af1 = *(const bf16x8*)(wc_ + 16);
        bf16x8 bf0 = *(const bf16x8*)(ac_);
        bf16x8 bf1 = *(const bf16x8*)(ac_ + 16);
        acc = MFMA32(af0, bf0, acc, 0, 0, 0);
        acc = MFMA32(af1, bf1, acc, 0, 0, 0);
        if (c < 3) {
            const int nb = cur ^ 1;
            #pragma unroll
            for (int j = 0; j < 4; ++j) {
                alds[nb][as][al8 + j][ai]     = (unsigned short)f2bf(na0[j] + na1[j]);
                alds[nb][as][al8 + 4 + j][ai] = (unsigned short)f2bf(na0b[j] + na1b[j]);
            }
            uint4 o_;
            o_.x = f2bf(nwa.x) | (f2bf(nwa.y) << 16);
            o_.y = f2bf(nwa.z) | (f2bf(nwa.w) << 16);
            o_.z = f2bf(nwb.x) | (f2bf(nwb.y) << 16);
            o_.w = f2bf(nwb.z) | (f2bf(nwb.w) << 16);
            *(uint4*)&wlds[nb][ws][wrow][wcolg] = o_;
            o_.x = f2bf(nwc.x) | (f2bf(nwc.y) << 16);
            o_.y = f2bf(nwc.z) | (f2bf(nwc.w) << 16);
            o_.z = f2bf(nwd.x) | (f2bf(nwd.y) << 16);
            o_.w = f2bf(nwd.z) | (f2bf(nwd.w) << 16);
            *(uint4*)&wlds[nb][ws][wrow][wcolg + 8] = o_;
        }
        __syncthreads();
    }

    // cross-wave K-half reduce
    if (khalf == 1) {
        #pragma unroll
        for (int reg = 0; reg < 16; ++reg) {
            const int orow = (reg & 3) + 8 * (reg >> 2) + 4 * hi;
            red[otile][orow][ln] = acc[reg];
        }
    }
    __syncthreads();
    if (khalf == 0) {
        #pragma unroll
        for (int reg = 0; reg < 16; ++reg) {
            const int orow = (reg & 3) + 8 * (reg >> 2) + 4 * hi;
            const int o = obase + otile * 32 + orow;
            const float inv = bnw[o] / sqrtf(bnv[o] + 1e-5f);
            const float sh  = bnb[o] - bnm[o] * inv;
            const size_t idx = ((size_t)b * CIN + o) * LL + l0 + ln;
            float val = acc[reg] + red[otile][orow][ln] + b_out[o] + x[idx];
            out[idx] = val * inv + sh;
        }
    }
}

// ---------------------------------------------------------------------------
extern "C" void kernel_launch(void* const* d_in, const int* in_sizes, int n_in,
                              void* d_out, int out_size, void* d_ws, size_t ws_size,
                              hipStream_t stream) {
    const float* x      = (const float*)d_in[0];
    const float* w_qkv  = (const float*)d_in[1];
    const float* b_qkv  = (const float*)d_in[2];
    const float* w_out  = (const float*)d_in[3];
    const float* b_out  = (const float*)d_in[4];
    const float* bnw    = (const float*)d_in[5];
    const float* bnb    = (const float*)d_in[6];
    const float* bnm    = (const float*)d_in[7];
    const float* bnv    = (const float*)d_in[8];
    float* out = (float*)d_out;

    const size_t NBH = (size_t)BB * HH;          // 32
    const size_t QKV_ELEMS = NBH * LL * CH;      // 2,097,152 bf16 elems each
    unsigned short* qb    = (unsigned short*)d_ws;
    unsigned short* kb    = qb + QKV_ELEMS;
    unsigned short* vtb   = kb + QKV_ELEMS;
    float* attnT = (float*)(vtb + QKV_ELEMS);    // 2 x 8 MB f32 partials

    qkv_mfma<<<dim3(32, 8, BB), 256, 0, stream>>>(x, w_qkv, b_qkv, qb, kb, vtb);
    denom_mfma<<<dim3(512), 512, 0, stream>>>(qb, kb, vtb);
    attn_mfma<<<dim3(512), 512, 0, stream>>>(qb, kb, vtb, attnT);
    out_mfma<<<dim3(512), 256, 0, stream>>>(attnT, w_out, x, b_out,
                                            bnw, bnb, bnm, bnv, out);
}